// Round 4
// baseline (1501.161 us; speedup 1.0000x reference)
//
#include <hip/hip_runtime.h>
#include <hip/hip_bf16.h>

// FraudGraphSAGE: 2-layer GraphSAGE (mean agg) + linear classifier.
// N=200000 nodes (12ch), E=3.2M edges.
//
// R4: layer1 rewritten: no shfl, no shared weights, no barriers.
//   - per-lane register weight columns (w1: 24 regs, w2: 64 regs)
//   - 4 nodes per wave-pass; inputs staged in wave-private LDS;
//     h stored transposed h_s[k][j] so ONE broadcast ds_read_b128 per k
//     feeds all 4 nodes in phase 2.
//   count_pos/scatter: 2 edges/thread, vectorized index loads, nt csr stores.

#define IN_CH 12
#define XPAD  16
#define HID   64
#define HID2  32
#define SCAN_BS  256
#define SCAN_EPB 2048

__global__ void detect_i64(const int* __restrict__ ei, int* __restrict__ flag) {
  if ((blockIdx.x | threadIdx.x) == 0) {
    *flag = ((ei[1] | ei[3] | ei[5] | ei[7]) == 0) ? 1 : 0;
  }
}

__global__ __launch_bounds__(256) void count_pos(
    const int* __restrict__ ei, int* __restrict__ deg,
    unsigned short* __restrict__ epos, const int* __restrict__ flag, int E) {
  int e = (blockIdx.x * 256 + threadIdx.x) * 2;
  if (e >= E) return;
  int f64 = *flag;
  if (e + 1 < E) {
    int d0, d1;
    if (f64) {
      int4 w = *(const int4*)(ei + 2 * ((size_t)E + e));
      d0 = w.x; d1 = w.z;
    } else {
      int2 w = *(const int2*)(ei + (size_t)E + e);
      d0 = w.x; d1 = w.y;
    }
    unsigned int p0 = (unsigned int)atomicAdd(&deg[d0], 1);
    unsigned int p1 = (unsigned int)atomicAdd(&deg[d1], 1);
    *(unsigned int*)(epos + e) = (p0 & 0xffffu) | (p1 << 16);
  } else {
    int d0 = f64 ? ei[2 * ((size_t)E + e)] : ei[(size_t)E + e];
    epos[e] = (unsigned short)atomicAdd(&deg[d0], 1);
  }
}

__global__ __launch_bounds__(SCAN_BS) void scan1(
    const int* __restrict__ deg, int* __restrict__ off,
    int* __restrict__ bsums, int N) {
  __shared__ int s[SCAN_BS];
  int t = threadIdx.x;
  int base = blockIdx.x * SCAN_EPB + t * 8;
  int v[8];
  int sum = 0;
#pragma unroll
  for (int i = 0; i < 8; ++i) { int idx = base + i; v[i] = (idx < N) ? deg[idx] : 0; sum += v[i]; }
  s[t] = sum;
  __syncthreads();
  for (int d = 1; d < SCAN_BS; d <<= 1) {
    int add = (t >= d) ? s[t - d] : 0;
    __syncthreads();
    s[t] += add;
    __syncthreads();
  }
  int run = s[t] - sum;
#pragma unroll
  for (int i = 0; i < 8; ++i) { int idx = base + i; if (idx < N) off[idx] = run; run += v[i]; }
  if (t == SCAN_BS - 1) bsums[blockIdx.x] = s[SCAN_BS - 1];
}

__global__ __launch_bounds__(SCAN_BS) void scan2(int* __restrict__ bsums, int P) {
  __shared__ int s[SCAN_BS];
  int t = threadIdx.x;
  int v[8];
  int sum = 0;
#pragma unroll
  for (int i = 0; i < 8; ++i) { int idx = t * 8 + i; v[i] = (idx < P) ? bsums[idx] : 0; sum += v[i]; }
  s[t] = sum;
  __syncthreads();
  for (int d = 1; d < SCAN_BS; d <<= 1) {
    int add = (t >= d) ? s[t - d] : 0;
    __syncthreads();
    s[t] += add;
    __syncthreads();
  }
  int run = s[t] - sum;
#pragma unroll
  for (int i = 0; i < 8; ++i) { int idx = t * 8 + i; if (idx < P) bsums[idx] = run; run += v[i]; }
}

__global__ __launch_bounds__(256) void scan3(
    int* __restrict__ off, const int* __restrict__ bsums, int N) {
  int i = blockIdx.x * 256 + threadIdx.x;
  if (i >= N) return;
  off[i] = off[i] + bsums[i / SCAN_EPB];
}

__global__ __launch_bounds__(256) void scatter_edges(
    const int* __restrict__ ei, const int* __restrict__ off,
    const unsigned short* __restrict__ epos, int* __restrict__ csr,
    const int* __restrict__ flag, int E) {
  int e = (blockIdx.x * 256 + threadIdx.x) * 2;
  if (e >= E) return;
  int f64 = *flag;
  if (e + 1 < E) {
    int s0, s1, d0, d1;
    if (f64) {
      int4 ws = *(const int4*)(ei + 2 * (size_t)e);
      int4 wd = *(const int4*)(ei + 2 * ((size_t)E + e));
      s0 = ws.x; s1 = ws.z; d0 = wd.x; d1 = wd.z;
    } else {
      int2 ws = *(const int2*)(ei + (size_t)e);
      int2 wd = *(const int2*)(ei + (size_t)E + e);
      s0 = ws.x; s1 = ws.y; d0 = wd.x; d1 = wd.y;
    }
    unsigned int pp = *(const unsigned int*)(epos + e);
    __builtin_nontemporal_store(s0, &csr[off[d0] + (int)(pp & 0xffffu)]);
    __builtin_nontemporal_store(s1, &csr[off[d1] + (int)(pp >> 16)]);
  } else {
    int s0 = f64 ? ei[2 * (size_t)e] : ei[e];
    int d0 = f64 ? ei[2 * ((size_t)E + e)] : ei[(size_t)E + e];
    __builtin_nontemporal_store(s0, &csr[off[d0] + (int)epos[e]]);
  }
}

__global__ __launch_bounds__(256) void xcast(
    const float* __restrict__ x, unsigned short* __restrict__ xh, int N) {
  int i = blockIdx.x * 256 + threadIdx.x;
  if (i >= N * XPAD) return;
  int n = i >> 4, c = i & 15;
  float v = (c < IN_CH) ? x[(size_t)n * IN_CH + c] : 0.f;
  union { float f; unsigned int u; } cv;
  cv.f = v;
  unsigned int b = cv.u;
  xh[i] = (unsigned short)((b + 0x7fffu + ((b >> 16) & 1u)) >> 16);
}

__global__ __launch_bounds__(256) void agg1_kernel(
    const int* __restrict__ off, const int* __restrict__ deg,
    const int* __restrict__ csr, const unsigned int* __restrict__ xh2,
    float* __restrict__ agg1, int N) {
  int tid = blockIdx.x * 256 + threadIdx.x;
  int node = tid >> 3;
  int l = tid & 7;
  if (node >= N || l >= 6) return;
  int start = off[node], d = deg[node];
  float a0 = 0.f, a1 = 0.f;
  int j = 0;
  for (; j + 1 < d; j += 2) {
    int s0 = csr[start + j], s1 = csr[start + j + 1];
    unsigned int w0 = xh2[(size_t)s0 * 8 + l];
    unsigned int w1 = xh2[(size_t)s1 * 8 + l];
    a0 += __uint_as_float(w0 << 16) + __uint_as_float(w1 << 16);
    a1 += __uint_as_float(w0 & 0xffff0000u) + __uint_as_float(w1 & 0xffff0000u);
  }
  if (j < d) {
    unsigned int w0 = xh2[(size_t)csr[start + j] * 8 + l];
    a0 += __uint_as_float(w0 << 16);
    a1 += __uint_as_float(w0 & 0xffff0000u);
  }
  int c = 2 * l;
  agg1[(size_t)node * IN_CH + c]     = a0;
  agg1[(size_t)node * IN_CH + c + 1] = a1;
}

__device__ __forceinline__ unsigned short f2bf(float f) {
  union { float f; unsigned int u; } cv; cv.f = f;
  unsigned int b = cv.u;
  return (unsigned short)((b + 0x7fffu + ((b >> 16) & 1u)) >> 16);
}

// 4 waves/block, each wave independently processes 4 nodes. No barriers.
__global__ __launch_bounds__(256, 3) void layer1_kernel(
    const float* __restrict__ x, const float* __restrict__ agg1,
    const int* __restrict__ deg,
    const float* __restrict__ w1l, const float* __restrict__ b1,
    const float* __restrict__ w1r, const float* __restrict__ w2l,
    const float* __restrict__ b2, const float* __restrict__ w2r,
    unsigned short* __restrict__ g, unsigned short* __restrict__ r, int N) {
  __shared__ float in_s[4][4][24];   // [wave][node j][ch: 0..11 agg*inv, 12..23 x]
  __shared__ float h_s[4][64][4];    // [wave][k][node j] transposed

  int t = threadIdx.x;
  int wave = t >> 6, lane = t & 63;
  int o = lane & 31;
  bool isg = lane < 32;

  // register weight columns
  float w1reg[24];
#pragma unroll
  for (int k = 0; k < 12; ++k) w1reg[k] = w1l[k * HID + lane];
#pragma unroll
  for (int k = 0; k < 12; ++k) w1reg[12 + k] = w1r[k * HID + lane];
  float b1reg = b1[lane];
  const float* W2 = isg ? w2l : w2r;
  float w2reg[64];
#pragma unroll
  for (int k = 0; k < 64; ++k) w2reg[k] = W2[k * HID2 + o];
  float bias2 = isg ? 0.0f : b2[o];

  int n4 = (blockIdx.x * 4 + wave) * 4;
  if (n4 >= N) return;

  // stage: 24 lanes load the 4 nodes' inputs (float4 each), scale agg by 1/deg
  if (lane < 24) {
    int part = lane / 12;            // 0 = agg1*inv, 1 = x
    int jj = (lane % 12) / 3, q = lane % 3;
    int n = n4 + jj;
    float4 v = make_float4(0.f, 0.f, 0.f, 0.f);
    if (n < N) {
      if (part == 0) {
        v = *(const float4*)(agg1 + (size_t)n * IN_CH + q * 4);
        float inv = 1.0f / fmaxf((float)deg[n], 1.0f);
        v.x *= inv; v.y *= inv; v.z *= inv; v.w *= inv;
      } else {
        v = *(const float4*)(x + (size_t)n * IN_CH + q * 4);
      }
    }
    *(float4*)&in_s[wave][jj][part * 12 + q * 4] = v;
  }

  // phase 1: h_j[lane] for j=0..3 via broadcast reads + register weights
#pragma unroll
  for (int j = 0; j < 4; ++j) {
    float acc = b1reg;
#pragma unroll
    for (int q = 0; q < 6; ++q) {
      float4 iv = *(const float4*)&in_s[wave][j][q * 4];
      acc = fmaf(iv.x, w1reg[q * 4 + 0], acc);
      acc = fmaf(iv.y, w1reg[q * 4 + 1], acc);
      acc = fmaf(iv.z, w1reg[q * 4 + 2], acc);
      acc = fmaf(iv.w, w1reg[q * 4 + 3], acc);
    }
    h_s[wave][lane][j] = fmaxf(acc, 0.0f);
  }

  // phase 2: one broadcast b128 per k serves all 4 nodes
  float a0 = bias2, a1 = bias2, a2 = bias2, a3 = bias2;
#pragma unroll
  for (int k = 0; k < 64; ++k) {
    float4 hv = *(const float4*)&h_s[wave][k][0];
    float wv = w2reg[k];
    a0 = fmaf(hv.x, wv, a0);
    a1 = fmaf(hv.y, wv, a1);
    a2 = fmaf(hv.z, wv, a2);
    a3 = fmaf(hv.w, wv, a3);
  }

  unsigned short* dstp = isg ? g : r;
  if (n4 + 0 < N) dstp[(size_t)(n4 + 0) * HID2 + o] = f2bf(a0);
  if (n4 + 1 < N) dstp[(size_t)(n4 + 1) * HID2 + o] = f2bf(a1);
  if (n4 + 2 < N) dstp[(size_t)(n4 + 2) * HID2 + o] = f2bf(a2);
  if (n4 + 3 < N) dstp[(size_t)(n4 + 3) * HID2 + o] = f2bf(a3);
}

__global__ __launch_bounds__(256) void agg2_final(
    const int* __restrict__ off, const int* __restrict__ deg,
    const int* __restrict__ csr, const unsigned short* __restrict__ g,
    const unsigned short* __restrict__ r, const float* __restrict__ wc,
    const float* __restrict__ bc, float* __restrict__ out, int N) {
  int tid = blockIdx.x * 256 + threadIdx.x;
  int node = tid >> 5;
  int lane = tid & 31;
  if (node >= N) return;
  int start = off[node], d = deg[node];
  float acc = 0.f;
  int j = 0;
  for (; j + 1 < d; j += 2) {
    int s0 = csr[start + j], s1 = csr[start + j + 1];
    unsigned int w0 = g[(size_t)s0 * HID2 + lane];
    unsigned int w1 = g[(size_t)s1 * HID2 + lane];
    acc += __uint_as_float(w0 << 16) + __uint_as_float(w1 << 16);
  }
  if (j < d) {
    unsigned int w0 = g[(size_t)csr[start + j] * HID2 + lane];
    acc += __uint_as_float(w0 << 16);
  }
  float dg = fmaxf((float)d, 1.0f);
  unsigned int rw = r[(size_t)node * HID2 + lane];
  float v = fmaxf(acc / dg + __uint_as_float(rw << 16), 0.0f);
  float p0 = v * wc[lane * 2 + 0];
  float p1 = v * wc[lane * 2 + 1];
#pragma unroll
  for (int o2 = 16; o2 > 0; o2 >>= 1) {
    p0 += __shfl_down(p0, o2, 32);
    p1 += __shfl_down(p1, o2, 32);
  }
  if (lane == 0) {
    out[(size_t)node * 2 + 0] = p0 + bc[0];
    out[(size_t)node * 2 + 1] = p1 + bc[1];
  }
}

extern "C" void kernel_launch(void* const* d_in, const int* in_sizes, int n_in,
                              void* d_out, int out_size, void* d_ws, size_t ws_size,
                              hipStream_t stream) {
  const float* x   = (const float*)d_in[0];
  const int*   ei  = (const int*)d_in[1];
  const float* w1l = (const float*)d_in[2];
  const float* b1  = (const float*)d_in[3];
  const float* w1r = (const float*)d_in[4];
  const float* w2l = (const float*)d_in[5];
  const float* b2  = (const float*)d_in[6];
  const float* w2r = (const float*)d_in[7];
  const float* wc  = (const float*)d_in[8];
  const float* bc  = (const float*)d_in[9];
  float* out = (float*)d_out;

  int N = in_sizes[0] / IN_CH;
  int E = in_sizes[1] / 2;

  int* deg   = (int*)d_ws;
  int* off   = deg + N;
  int* bsums = off + N;
  int* flag  = bsums + 2048;
  int* csr   = flag + 1;
  float* agg1 = (float*)(csr + E);
  unsigned short* epos = (unsigned short*)(agg1 + (size_t)N * IN_CH);
  unsigned short* xh   = epos + E;
  unsigned short* g    = xh + (size_t)N * XPAD;
  unsigned short* r    = g + (size_t)N * HID2;

  hipMemsetAsync(deg, 0, sizeof(int) * (size_t)N, stream);
  detect_i64<<<1, 64, 0, stream>>>(ei, flag);

  int e2blocks = ((E + 1) / 2 + 255) / 256;
  count_pos<<<e2blocks, 256, 0, stream>>>(ei, deg, epos, flag, E);

  xcast<<<((size_t)N * XPAD + 255) / 256, 256, 0, stream>>>(x, xh, N);

  int P = (N + SCAN_EPB - 1) / SCAN_EPB;
  scan1<<<P, SCAN_BS, 0, stream>>>(deg, off, bsums, N);
  scan2<<<1, SCAN_BS, 0, stream>>>(bsums, P);
  scan3<<<(N + 255) / 256, 256, 0, stream>>>(off, bsums, N);

  scatter_edges<<<e2blocks, 256, 0, stream>>>(ei, off, epos, csr, flag, E);

  agg1_kernel<<<((size_t)N * 8 + 255) / 256, 256, 0, stream>>>(
      off, deg, csr, (const unsigned int*)xh, agg1, N);

  int l1blocks = (N + 15) / 16;
  layer1_kernel<<<l1blocks, 256, 0, stream>>>(x, agg1, deg, w1l, b1, w1r,
                                              w2l, b2, w2r, g, r, N);

  agg2_final<<<((size_t)N * 32 + 255) / 256, 256, 0, stream>>>(
      off, deg, csr, g, r, wc, bc, out, N);
}

// Round 5
// 635.701 us; speedup vs baseline: 2.3614x; 2.3614x over previous
//
#include <hip/hip_runtime.h>
#include <hip/hip_bf16.h>

// FraudGraphSAGE: 2-layer GraphSAGE (mean agg) + linear classifier.
// N=200000 nodes (12ch), E=3.2M edges.
//
// R5: layer1 fixed after R4 spill regression:
//   - w2 in LDS (16KB, 2-way-free bank pattern), w1 in 24 regs (no spill)
//   - 4 nodes/wave-pass, h transposed in LDS -> broadcast b128 per k
//   - persistent blocks w/ grid-stride loop (weights loaded once per block)
//   count_pos/scatter: 2 edges/thread, vectorized index loads, nt csr stores.

#define IN_CH 12
#define XPAD  16
#define HID   64
#define HID2  32
#define SCAN_BS  256
#define SCAN_EPB 2048

__global__ void detect_i64(const int* __restrict__ ei, int* __restrict__ flag) {
  if ((blockIdx.x | threadIdx.x) == 0) {
    *flag = ((ei[1] | ei[3] | ei[5] | ei[7]) == 0) ? 1 : 0;
  }
}

__global__ __launch_bounds__(256) void count_pos(
    const int* __restrict__ ei, int* __restrict__ deg,
    unsigned short* __restrict__ epos, const int* __restrict__ flag, int E) {
  int e = (blockIdx.x * 256 + threadIdx.x) * 2;
  if (e >= E) return;
  int f64 = *flag;
  if (e + 1 < E) {
    int d0, d1;
    if (f64) {
      int4 w = *(const int4*)(ei + 2 * ((size_t)E + e));
      d0 = w.x; d1 = w.z;
    } else {
      int2 w = *(const int2*)(ei + (size_t)E + e);
      d0 = w.x; d1 = w.y;
    }
    unsigned int p0 = (unsigned int)atomicAdd(&deg[d0], 1);
    unsigned int p1 = (unsigned int)atomicAdd(&deg[d1], 1);
    *(unsigned int*)(epos + e) = (p0 & 0xffffu) | (p1 << 16);
  } else {
    int d0 = f64 ? ei[2 * ((size_t)E + e)] : ei[(size_t)E + e];
    epos[e] = (unsigned short)atomicAdd(&deg[d0], 1);
  }
}

__global__ __launch_bounds__(SCAN_BS) void scan1(
    const int* __restrict__ deg, int* __restrict__ off,
    int* __restrict__ bsums, int N) {
  __shared__ int s[SCAN_BS];
  int t = threadIdx.x;
  int base = blockIdx.x * SCAN_EPB + t * 8;
  int v[8];
  int sum = 0;
#pragma unroll
  for (int i = 0; i < 8; ++i) { int idx = base + i; v[i] = (idx < N) ? deg[idx] : 0; sum += v[i]; }
  s[t] = sum;
  __syncthreads();
  for (int d = 1; d < SCAN_BS; d <<= 1) {
    int add = (t >= d) ? s[t - d] : 0;
    __syncthreads();
    s[t] += add;
    __syncthreads();
  }
  int run = s[t] - sum;
#pragma unroll
  for (int i = 0; i < 8; ++i) { int idx = base + i; if (idx < N) off[idx] = run; run += v[i]; }
  if (t == SCAN_BS - 1) bsums[blockIdx.x] = s[SCAN_BS - 1];
}

__global__ __launch_bounds__(SCAN_BS) void scan2(int* __restrict__ bsums, int P) {
  __shared__ int s[SCAN_BS];
  int t = threadIdx.x;
  int v[8];
  int sum = 0;
#pragma unroll
  for (int i = 0; i < 8; ++i) { int idx = t * 8 + i; v[i] = (idx < P) ? bsums[idx] : 0; sum += v[i]; }
  s[t] = sum;
  __syncthreads();
  for (int d = 1; d < SCAN_BS; d <<= 1) {
    int add = (t >= d) ? s[t - d] : 0;
    __syncthreads();
    s[t] += add;
    __syncthreads();
  }
  int run = s[t] - sum;
#pragma unroll
  for (int i = 0; i < 8; ++i) { int idx = t * 8 + i; if (idx < P) bsums[idx] = run; run += v[i]; }
}

__global__ __launch_bounds__(256) void scan3(
    int* __restrict__ off, const int* __restrict__ bsums, int N) {
  int i = blockIdx.x * 256 + threadIdx.x;
  if (i >= N) return;
  off[i] = off[i] + bsums[i / SCAN_EPB];
}

__global__ __launch_bounds__(256) void scatter_edges(
    const int* __restrict__ ei, const int* __restrict__ off,
    const unsigned short* __restrict__ epos, int* __restrict__ csr,
    const int* __restrict__ flag, int E) {
  int e = (blockIdx.x * 256 + threadIdx.x) * 2;
  if (e >= E) return;
  int f64 = *flag;
  if (e + 1 < E) {
    int s0, s1, d0, d1;
    if (f64) {
      int4 ws = *(const int4*)(ei + 2 * (size_t)e);
      int4 wd = *(const int4*)(ei + 2 * ((size_t)E + e));
      s0 = ws.x; s1 = ws.z; d0 = wd.x; d1 = wd.z;
    } else {
      int2 ws = *(const int2*)(ei + (size_t)e);
      int2 wd = *(const int2*)(ei + (size_t)E + e);
      s0 = ws.x; s1 = ws.y; d0 = wd.x; d1 = wd.y;
    }
    unsigned int pp = *(const unsigned int*)(epos + e);
    __builtin_nontemporal_store(s0, &csr[off[d0] + (int)(pp & 0xffffu)]);
    __builtin_nontemporal_store(s1, &csr[off[d1] + (int)(pp >> 16)]);
  } else {
    int s0 = f64 ? ei[2 * (size_t)e] : ei[e];
    int d0 = f64 ? ei[2 * ((size_t)E + e)] : ei[(size_t)E + e];
    __builtin_nontemporal_store(s0, &csr[off[d0] + (int)epos[e]]);
  }
}

__global__ __launch_bounds__(256) void xcast(
    const float* __restrict__ x, unsigned short* __restrict__ xh, int N) {
  int i = blockIdx.x * 256 + threadIdx.x;
  if (i >= N * XPAD) return;
  int n = i >> 4, c = i & 15;
  float v = (c < IN_CH) ? x[(size_t)n * IN_CH + c] : 0.f;
  union { float f; unsigned int u; } cv;
  cv.f = v;
  unsigned int b = cv.u;
  xh[i] = (unsigned short)((b + 0x7fffu + ((b >> 16) & 1u)) >> 16);
}

__global__ __launch_bounds__(256) void agg1_kernel(
    const int* __restrict__ off, const int* __restrict__ deg,
    const int* __restrict__ csr, const unsigned int* __restrict__ xh2,
    float* __restrict__ agg1, int N) {
  int tid = blockIdx.x * 256 + threadIdx.x;
  int node = tid >> 3;
  int l = tid & 7;
  if (node >= N || l >= 6) return;
  int start = off[node], d = deg[node];
  float a0 = 0.f, a1 = 0.f;
  int j = 0;
  for (; j + 1 < d; j += 2) {
    int s0 = csr[start + j], s1 = csr[start + j + 1];
    unsigned int w0 = xh2[(size_t)s0 * 8 + l];
    unsigned int w1 = xh2[(size_t)s1 * 8 + l];
    a0 += __uint_as_float(w0 << 16) + __uint_as_float(w1 << 16);
    a1 += __uint_as_float(w0 & 0xffff0000u) + __uint_as_float(w1 & 0xffff0000u);
  }
  if (j < d) {
    unsigned int w0 = xh2[(size_t)csr[start + j] * 8 + l];
    a0 += __uint_as_float(w0 << 16);
    a1 += __uint_as_float(w0 & 0xffff0000u);
  }
  int c = 2 * l;
  agg1[(size_t)node * IN_CH + c]     = a0;
  agg1[(size_t)node * IN_CH + c + 1] = a1;
}

__device__ __forceinline__ unsigned short f2bf(float f) {
  union { float f; unsigned int u; } cv; cv.f = f;
  unsigned int b = cv.u;
  return (unsigned short)((b + 0x7fffu + ((b >> 16) & 1u)) >> 16);
}

// Persistent blocks; 4 waves/block; each wave handles 4 nodes per pass.
// w2 in LDS (2-way-free reads), w1 in 24 regs, h transposed in wave-private
// LDS so phase 2 uses broadcast b128 reads. One barrier total (w2 stage).
__global__ __launch_bounds__(256) void layer1_kernel(
    const float* __restrict__ x, const float* __restrict__ agg1,
    const int* __restrict__ deg,
    const float* __restrict__ w1l, const float* __restrict__ b1,
    const float* __restrict__ w1r, const float* __restrict__ w2l,
    const float* __restrict__ b2, const float* __restrict__ w2r,
    unsigned short* __restrict__ g, unsigned short* __restrict__ r, int N) {
  __shared__ float s_w2[2][HID * HID2];  // [0]=w2l, [1]=w2r (8KB each)
  __shared__ float in_s[4][4][24];       // [wave][node j][0..11 mean, 12..23 x]
  __shared__ float h_s[4][64][4];        // [wave][k][node j]

  int t = threadIdx.x;
  for (int i = t; i < HID * HID2; i += 256) {
    s_w2[0][i] = w2l[i];
    s_w2[1][i] = w2r[i];
  }
  int wave = t >> 6, lane = t & 63;
  int o = lane & 31;
  bool isg = lane < 32;

  float w1reg[24];
#pragma unroll
  for (int k = 0; k < 12; ++k) w1reg[k] = w1l[k * HID + lane];
#pragma unroll
  for (int k = 0; k < 12; ++k) w1reg[12 + k] = w1r[k * HID + lane];
  float b1reg = b1[lane];
  float bias2 = isg ? 0.0f : b2[o];
  const float* w2col = &s_w2[isg ? 0 : 1][o];
  unsigned short* dstp = isg ? g : r;
  __syncthreads();

  // staging role for this lane (constant across passes)
  int part = lane / 12;                 // 0 = mean (agg1*inv), 1 = x
  int jj = (lane % 12) / 3, q = lane % 3;

  int ngroups = (N + 3) >> 2;
  for (int grp = blockIdx.x * 4 + wave; grp < ngroups; grp += gridDim.x * 4) {
    int n4 = grp * 4;

    if (lane < 24) {
      int n = n4 + jj;
      float4 v = make_float4(0.f, 0.f, 0.f, 0.f);
      if (n < N) {
        if (part == 0) {
          v = *(const float4*)(agg1 + (size_t)n * IN_CH + q * 4);
          float inv = 1.0f / fmaxf((float)deg[n], 1.0f);
          v.x *= inv; v.y *= inv; v.z *= inv; v.w *= inv;
        } else {
          v = *(const float4*)(x + (size_t)n * IN_CH + q * 4);
        }
      }
      *(float4*)&in_s[wave][jj][part * 12 + q * 4] = v;
    }

    // phase 1: h for 4 nodes (broadcast in_s reads x register weights)
#pragma unroll
    for (int j = 0; j < 4; ++j) {
      float acc = b1reg;
#pragma unroll
      for (int qq = 0; qq < 6; ++qq) {
        float4 iv = *(const float4*)&in_s[wave][j][qq * 4];
        acc = fmaf(iv.x, w1reg[qq * 4 + 0], acc);
        acc = fmaf(iv.y, w1reg[qq * 4 + 1], acc);
        acc = fmaf(iv.z, w1reg[qq * 4 + 2], acc);
        acc = fmaf(iv.w, w1reg[qq * 4 + 3], acc);
      }
      h_s[wave][lane][j] = fmaxf(acc, 0.0f);
    }

    // phase 2: per k one broadcast b128 (h of 4 nodes) + one b32 (w2)
    float a0 = bias2, a1 = bias2, a2 = bias2, a3 = bias2;
#pragma unroll
    for (int k = 0; k < 64; ++k) {
      float4 hv = *(const float4*)&h_s[wave][k][0];
      float wv = w2col[k * HID2];
      a0 = fmaf(hv.x, wv, a0);
      a1 = fmaf(hv.y, wv, a1);
      a2 = fmaf(hv.z, wv, a2);
      a3 = fmaf(hv.w, wv, a3);
    }

    if (n4 + 0 < N) dstp[(size_t)(n4 + 0) * HID2 + o] = f2bf(a0);
    if (n4 + 1 < N) dstp[(size_t)(n4 + 1) * HID2 + o] = f2bf(a1);
    if (n4 + 2 < N) dstp[(size_t)(n4 + 2) * HID2 + o] = f2bf(a2);
    if (n4 + 3 < N) dstp[(size_t)(n4 + 3) * HID2 + o] = f2bf(a3);
  }
}

__global__ __launch_bounds__(256) void agg2_final(
    const int* __restrict__ off, const int* __restrict__ deg,
    const int* __restrict__ csr, const unsigned short* __restrict__ g,
    const unsigned short* __restrict__ r, const float* __restrict__ wc,
    const float* __restrict__ bc, float* __restrict__ out, int N) {
  int tid = blockIdx.x * 256 + threadIdx.x;
  int node = tid >> 5;
  int lane = tid & 31;
  if (node >= N) return;
  int start = off[node], d = deg[node];
  float acc = 0.f;
  int j = 0;
  for (; j + 1 < d; j += 2) {
    int s0 = csr[start + j], s1 = csr[start + j + 1];
    unsigned int w0 = g[(size_t)s0 * HID2 + lane];
    unsigned int w1 = g[(size_t)s1 * HID2 + lane];
    acc += __uint_as_float(w0 << 16) + __uint_as_float(w1 << 16);
  }
  if (j < d) {
    unsigned int w0 = g[(size_t)csr[start + j] * HID2 + lane];
    acc += __uint_as_float(w0 << 16);
  }
  float dg = fmaxf((float)d, 1.0f);
  unsigned int rw = r[(size_t)node * HID2 + lane];
  float v = fmaxf(acc / dg + __uint_as_float(rw << 16), 0.0f);
  float p0 = v * wc[lane * 2 + 0];
  float p1 = v * wc[lane * 2 + 1];
#pragma unroll
  for (int o2 = 16; o2 > 0; o2 >>= 1) {
    p0 += __shfl_down(p0, o2, 32);
    p1 += __shfl_down(p1, o2, 32);
  }
  if (lane == 0) {
    out[(size_t)node * 2 + 0] = p0 + bc[0];
    out[(size_t)node * 2 + 1] = p1 + bc[1];
  }
}

extern "C" void kernel_launch(void* const* d_in, const int* in_sizes, int n_in,
                              void* d_out, int out_size, void* d_ws, size_t ws_size,
                              hipStream_t stream) {
  const float* x   = (const float*)d_in[0];
  const int*   ei  = (const int*)d_in[1];
  const float* w1l = (const float*)d_in[2];
  const float* b1  = (const float*)d_in[3];
  const float* w1r = (const float*)d_in[4];
  const float* w2l = (const float*)d_in[5];
  const float* b2  = (const float*)d_in[6];
  const float* w2r = (const float*)d_in[7];
  const float* wc  = (const float*)d_in[8];
  const float* bc  = (const float*)d_in[9];
  float* out = (float*)d_out;

  int N = in_sizes[0] / IN_CH;
  int E = in_sizes[1] / 2;

  int* deg   = (int*)d_ws;
  int* off   = deg + N;
  int* bsums = off + N;
  int* flag  = bsums + 2048;
  int* csr   = flag + 1;
  float* agg1 = (float*)(csr + E);
  unsigned short* epos = (unsigned short*)(agg1 + (size_t)N * IN_CH);
  unsigned short* xh   = epos + E;
  unsigned short* g    = xh + (size_t)N * XPAD;
  unsigned short* r    = g + (size_t)N * HID2;

  hipMemsetAsync(deg, 0, sizeof(int) * (size_t)N, stream);
  detect_i64<<<1, 64, 0, stream>>>(ei, flag);

  int e2blocks = ((E + 1) / 2 + 255) / 256;
  count_pos<<<e2blocks, 256, 0, stream>>>(ei, deg, epos, flag, E);

  xcast<<<((size_t)N * XPAD + 255) / 256, 256, 0, stream>>>(x, xh, N);

  int P = (N + SCAN_EPB - 1) / SCAN_EPB;
  scan1<<<P, SCAN_BS, 0, stream>>>(deg, off, bsums, N);
  scan2<<<1, SCAN_BS, 0, stream>>>(bsums, P);
  scan3<<<(N + 255) / 256, 256, 0, stream>>>(off, bsums, N);

  scatter_edges<<<e2blocks, 256, 0, stream>>>(ei, off, epos, csr, flag, E);

  agg1_kernel<<<((size_t)N * 8 + 255) / 256, 256, 0, stream>>>(
      off, deg, csr, (const unsigned int*)xh, agg1, N);

  layer1_kernel<<<1024, 256, 0, stream>>>(x, agg1, deg, w1l, b1, w1r,
                                          w2l, b2, w2r, g, r, N);

  agg2_final<<<((size_t)N * 32 + 255) / 256, 256, 0, stream>>>(
      off, deg, csr, g, r, wc, bc, out, N);
}

// Round 7
// 523.398 us; speedup vs baseline: 2.8681x; 1.2146x over previous
//
#include <hip/hip_runtime.h>
#include <hip/hip_bf16.h>

// FraudGraphSAGE: 2-layer GraphSAGE (mean agg) + linear classifier.
// N=200000 nodes (12ch), E=3.2M edges.
//
// R6: layer1 via MFMA (16x16x32 bf16), transposed orientation:
//   D[ch][node] = Wt-frag (A) x node-frag (B). Per 16-node tile/wave:
//   1 global b128 (inputs) + 4 MFMA (GEMM1) + 4 ds_write_b64 (h, swizzled)
//   + 2 ds_read_b128 + 8 MFMA (GEMM2) + 4 uint2 global stores. Weights
//   prepacked into lane-fragments by prep_frags (runs once, 12x64 threads).
//   in_bf[n][32] bf16 = [mean(12)|pad4|x(12)|pad4]: K1=32 exactly, K2=64.
//   CSR build (count_pos epos trick + scan + atomic-free scatter) unchanged.

#define IN_CH 12
#define HID   64
#define HID2  32
#define SCAN_BS  256
#define SCAN_EPB 2048

using f32x4  = __attribute__((ext_vector_type(4))) float;
using bf16x8 = __attribute__((ext_vector_type(8))) short;

__device__ __forceinline__ unsigned short f2bf(float f) {
  union { float f; unsigned int u; } cv; cv.f = f;
  unsigned int b = cv.u;
  return (unsigned short)((b + 0x7fffu + ((b >> 16) & 1u)) >> 16);
}
__device__ __forceinline__ unsigned int packbf(float a, float b) {
  return (unsigned int)f2bf(a) | ((unsigned int)f2bf(b) << 16);
}

__global__ void detect_i64(const int* __restrict__ ei, int* __restrict__ flag) {
  if ((blockIdx.x | threadIdx.x) == 0) {
    *flag = ((ei[1] | ei[3] | ei[5] | ei[7]) == 0) ? 1 : 0;
  }
}

__global__ __launch_bounds__(256) void count_pos(
    const int* __restrict__ ei, int* __restrict__ deg,
    unsigned short* __restrict__ epos, const int* __restrict__ flag, int E) {
  int e = (blockIdx.x * 256 + threadIdx.x) * 2;
  if (e >= E) return;
  int f64 = *flag;
  if (e + 1 < E) {
    int d0, d1;
    if (f64) {
      int4 w = *(const int4*)(ei + 2 * ((size_t)E + e));
      d0 = w.x; d1 = w.z;
    } else {
      int2 w = *(const int2*)(ei + (size_t)E + e);
      d0 = w.x; d1 = w.y;
    }
    unsigned int p0 = (unsigned int)atomicAdd(&deg[d0], 1);
    unsigned int p1 = (unsigned int)atomicAdd(&deg[d1], 1);
    *(unsigned int*)(epos + e) = (p0 & 0xffffu) | (p1 << 16);
  } else {
    int d0 = f64 ? ei[2 * ((size_t)E + e)] : ei[(size_t)E + e];
    epos[e] = (unsigned short)atomicAdd(&deg[d0], 1);
  }
}

__global__ __launch_bounds__(SCAN_BS) void scan1(
    const int* __restrict__ deg, int* __restrict__ off,
    int* __restrict__ bsums, int N) {
  __shared__ int s[SCAN_BS];
  int t = threadIdx.x;
  int base = blockIdx.x * SCAN_EPB + t * 8;
  int v[8];
  int sum = 0;
#pragma unroll
  for (int i = 0; i < 8; ++i) { int idx = base + i; v[i] = (idx < N) ? deg[idx] : 0; sum += v[i]; }
  s[t] = sum;
  __syncthreads();
  for (int d = 1; d < SCAN_BS; d <<= 1) {
    int add = (t >= d) ? s[t - d] : 0;
    __syncthreads();
    s[t] += add;
    __syncthreads();
  }
  int run = s[t] - sum;
#pragma unroll
  for (int i = 0; i < 8; ++i) { int idx = base + i; if (idx < N) off[idx] = run; run += v[i]; }
  if (t == SCAN_BS - 1) bsums[blockIdx.x] = s[SCAN_BS - 1];
}

__global__ __launch_bounds__(SCAN_BS) void scan2(int* __restrict__ bsums, int P) {
  __shared__ int s[SCAN_BS];
  int t = threadIdx.x;
  int v[8];
  int sum = 0;
#pragma unroll
  for (int i = 0; i < 8; ++i) { int idx = t * 8 + i; v[i] = (idx < P) ? bsums[idx] : 0; sum += v[i]; }
  s[t] = sum;
  __syncthreads();
  for (int d = 1; d < SCAN_BS; d <<= 1) {
    int add = (t >= d) ? s[t - d] : 0;
    __syncthreads();
    s[t] += add;
    __syncthreads();
  }
  int run = s[t] - sum;
#pragma unroll
  for (int i = 0; i < 8; ++i) { int idx = t * 8 + i; if (idx < P) bsums[idx] = run; run += v[i]; }
}

__global__ __launch_bounds__(256) void scan3(
    int* __restrict__ off, const int* __restrict__ bsums, int N) {
  int i = blockIdx.x * 256 + threadIdx.x;
  if (i >= N) return;
  off[i] = off[i] + bsums[i / SCAN_EPB];
}

__global__ __launch_bounds__(256) void scatter_edges(
    const int* __restrict__ ei, const int* __restrict__ off,
    const unsigned short* __restrict__ epos, int* __restrict__ csr,
    const int* __restrict__ flag, int E) {
  int e = (blockIdx.x * 256 + threadIdx.x) * 2;
  if (e >= E) return;
  int f64 = *flag;
  if (e + 1 < E) {
    int s0, s1, d0, d1;
    if (f64) {
      int4 ws = *(const int4*)(ei + 2 * (size_t)e);
      int4 wd = *(const int4*)(ei + 2 * ((size_t)E + e));
      s0 = ws.x; s1 = ws.z; d0 = wd.x; d1 = wd.z;
    } else {
      int2 ws = *(const int2*)(ei + (size_t)e);
      int2 wd = *(const int2*)(ei + (size_t)E + e);
      s0 = ws.x; s1 = ws.y; d0 = wd.x; d1 = wd.y;
    }
    unsigned int pp = *(const unsigned int*)(epos + e);
    __builtin_nontemporal_store(s0, &csr[off[d0] + (int)(pp & 0xffffu)]);
    __builtin_nontemporal_store(s1, &csr[off[d1] + (int)(pp >> 16)]);
  } else {
    int s0 = f64 ? ei[2 * (size_t)e] : ei[e];
    int d0 = f64 ? ei[2 * ((size_t)E + e)] : ei[(size_t)E + e];
    __builtin_nontemporal_store(s0, &csr[off[d0] + (int)epos[e]]);
  }
}

// Writes x-half of in_bf: u32 slots 8..15 of each 16-u32 row.
__global__ __launch_bounds__(256) void xcast(
    const float* __restrict__ x, unsigned int* __restrict__ inb32, int N) {
  int i = blockIdx.x * 256 + threadIdx.x;
  if (i >= N * 8) return;
  int n = i >> 3, cp = i & 7;  // channel pair
  unsigned int w = 0;
  if (cp < 6) {
    float2 v = *(const float2*)(x + (size_t)n * IN_CH + cp * 2);
    w = packbf(v.x, v.y);
  }
  inb32[(size_t)n * 16 + 8 + cp] = w;
}

// Gathers neighbor x (bf16, from x-half of in_bf) and writes bf16 MEAN into
// the mean-half (u32 slots 0..7). Read/write halves are disjoint.
__global__ __launch_bounds__(256) void agg1_mean(
    const int* __restrict__ off, const int* __restrict__ deg,
    const int* __restrict__ csr, unsigned int* __restrict__ inb32, int N) {
  int tid = blockIdx.x * 256 + threadIdx.x;
  int node = tid >> 3;
  int l = tid & 7;
  if (node >= N) return;
  unsigned int* row = inb32 + (size_t)node * 16;
  if (l >= 6) { row[l] = 0; return; }  // pad ch 12..15
  int start = off[node], d = deg[node];
  float a0 = 0.f, a1 = 0.f;
  int j = 0;
  for (; j + 1 < d; j += 2) {
    int s0 = csr[start + j], s1 = csr[start + j + 1];
    unsigned int w0 = inb32[(size_t)s0 * 16 + 8 + l];
    unsigned int w1 = inb32[(size_t)s1 * 16 + 8 + l];
    a0 += __uint_as_float(w0 << 16) + __uint_as_float(w1 << 16);
    a1 += __uint_as_float(w0 & 0xffff0000u) + __uint_as_float(w1 & 0xffff0000u);
  }
  if (j < d) {
    unsigned int w0 = inb32[(size_t)csr[start + j] * 16 + 8 + l];
    a0 += __uint_as_float(w0 << 16);
    a1 += __uint_as_float(w0 & 0xffff0000u);
  }
  float inv = 1.0f / fmaxf((float)d, 1.0f);
  row[l] = packbf(a0 * inv, a1 * inv);
}

// Prepack weight fragments (A-operand, transposed orientation).
// frag f: 0..3  = GEMM1 tile t1 (w1 stacked: k<12 w1l, 16<=k<28 w1r, else 0)
//         4..11 = GEMM2 (t2 = (f-4)>>1, half = (f-4)&1; t2<2 w2l else w2r)
// lane l: m-index = l&15, k = (l>>4)*8 + i.
__global__ void prep_frags(
    const float* __restrict__ w1l, const float* __restrict__ w1r,
    const float* __restrict__ w2l, const float* __restrict__ w2r,
    unsigned int* __restrict__ wfrag) {
  int f = blockIdx.x, l = threadIdx.x;
  int q = l >> 4, c = l & 15;
  unsigned int out[4];
#pragma unroll
  for (int p = 0; p < 4; ++p) {
    float v[2];
#pragma unroll
    for (int s = 0; s < 2; ++s) {
      int i = 2 * p + s;
      float val = 0.f;
      if (f < 4) {
        int k = q * 8 + i, ch = f * 16 + c;
        if (k < 12) val = w1l[k * HID + ch];
        else if (k >= 16 && k < 28) val = w1r[(k - 16) * HID + ch];
      } else {
        int t2 = (f - 4) >> 1, half = (f - 4) & 1;
        int k = half * 32 + q * 8 + i;
        int oc = t2 * 16 + c;
        val = (t2 < 2) ? w2l[k * HID2 + oc] : w2r[k * HID2 + (oc - 32)];
      }
      v[s] = val;
    }
    out[p] = packbf(v[0], v[1]);
  }
  *(uint4*)&wfrag[(f * 64 + l) * 4] = make_uint4(out[0], out[1], out[2], out[3]);
}

// Per wave: one 16-node tile per pass (grid-stride). h staged in wave-private
// LDS, bf16, XOR-swizzled (granule ^ (node&7)) -> 2-way (free) reads.
__global__ __launch_bounds__(256) void layer1_mfma(
    const unsigned short* __restrict__ in_bf, const unsigned int* __restrict__ wfrag,
    const float* __restrict__ b1, const float* __restrict__ b2,
    unsigned short* __restrict__ g, unsigned short* __restrict__ r, int N) {
  __shared__ unsigned int s_h[4][512];  // [wave][node(16) x 32 u32] = 2KB/wave
  int t = threadIdx.x, wave = t >> 6, l = t & 63;
  int q = l >> 4, c = l & 15;
  int swz = c & 7;

  union FU { uint4 u4; bf16x8 v; } fu;
  bf16x8 a1[4], a2[8];
#pragma unroll
  for (int f = 0; f < 4; ++f) { fu.u4 = ((const uint4*)wfrag)[f * 64 + l]; a1[f] = fu.v; }
#pragma unroll
  for (int f = 0; f < 8; ++f) { fu.u4 = ((const uint4*)wfrag)[(4 + f) * 64 + l]; a2[f] = fu.v; }

  f32x4 c1[4], c2[4];
#pragma unroll
  for (int t1 = 0; t1 < 4; ++t1) {
    float4 bv = *(const float4*)(b1 + t1 * 16 + q * 4);
    c1[t1][0] = bv.x; c1[t1][1] = bv.y; c1[t1][2] = bv.z; c1[t1][3] = bv.w;
  }
#pragma unroll
  for (int t2 = 0; t2 < 4; ++t2) {
    if (t2 < 2) { c2[t2][0] = 0.f; c2[t2][1] = 0.f; c2[t2][2] = 0.f; c2[t2][3] = 0.f; }
    else {
      float4 bv = *(const float4*)(b2 + (t2 - 2) * 16 + q * 4);
      c2[t2][0] = bv.x; c2[t2][1] = bv.y; c2[t2][2] = bv.z; c2[t2][3] = bv.w;
    }
  }

  int ntiles = (N + 15) >> 4;
  for (int tile = blockIdx.x * 4 + wave; tile < ntiles; tile += gridDim.x * 4) {
    int node_g = tile * 16 + c;
    int ng = node_g < N ? node_g : N - 1;
    fu.u4 = ((const uint4*)in_bf)[(size_t)ng * 4 + q];
    bf16x8 bfrag = fu.v;

    // GEMM1: h[ch][node] per tile; relu; pack; swizzled LDS write (b64)
#pragma unroll
    for (int t1 = 0; t1 < 4; ++t1) {
      f32x4 d = __builtin_amdgcn_mfma_f32_16x16x32_bf16(a1[t1], bfrag, c1[t1], 0, 0, 0);
      unsigned int lo = packbf(fmaxf(d[0], 0.f), fmaxf(d[1], 0.f));
      unsigned int hi = packbf(fmaxf(d[2], 0.f), fmaxf(d[3], 0.f));
      int gr = (t1 * 2 + (q >> 1)) ^ swz;
      int idx = c * 32 + gr * 4 + (q & 1) * 2;
      *(uint2*)&s_h[wave][idx] = make_uint2(lo, hi);
    }
    __builtin_amdgcn_wave_barrier();

    // read h-fragments (B operand of GEMM2): node=c, k=(l>>4)*8+i per half
    bf16x8 hf0, hf1;
    fu.u4 = *(const uint4*)&s_h[wave][c * 32 + ((q) ^ swz) * 4];       hf0 = fu.v;
    fu.u4 = *(const uint4*)&s_h[wave][c * 32 + ((4 + q) ^ swz) * 4];   hf1 = fu.v;

    if (node_g < N) {
      size_t gb = (size_t)node_g * HID2;
#pragma unroll
      for (int t2 = 0; t2 < 4; ++t2) {
        f32x4 d = __builtin_amdgcn_mfma_f32_16x16x32_bf16(a2[t2 * 2 + 0], hf0, c2[t2], 0, 0, 0);
        d = __builtin_amdgcn_mfma_f32_16x16x32_bf16(a2[t2 * 2 + 1], hf1, d, 0, 0, 0);
        unsigned int lo = packbf(d[0], d[1]);
        unsigned int hi = packbf(d[2], d[3]);
        unsigned short* dst = (t2 < 2) ? g : r;
        int ch = (t2 & 1) * 16 + q * 4;
        *(uint2*)(dst + gb + ch) = make_uint2(lo, hi);
      }
    }
    __builtin_amdgcn_wave_barrier();
  }
}

__global__ __launch_bounds__(256) void agg2_final(
    const int* __restrict__ off, const int* __restrict__ deg,
    const int* __restrict__ csr, const unsigned short* __restrict__ g,
    const unsigned short* __restrict__ r, const float* __restrict__ wc,
    const float* __restrict__ bc, float* __restrict__ out, int N) {
  int tid = blockIdx.x * 256 + threadIdx.x;
  int node = tid >> 5;
  int lane = tid & 31;
  if (node >= N) return;
  int start = off[node], d = deg[node];
  float acc = 0.f;
  int j = 0;
  for (; j + 1 < d; j += 2) {
    int s0 = csr[start + j], s1 = csr[start + j + 1];
    unsigned int w0 = g[(size_t)s0 * HID2 + lane];
    unsigned int w1 = g[(size_t)s1 * HID2 + lane];
    acc += __uint_as_float(w0 << 16) + __uint_as_float(w1 << 16);
  }
  if (j < d) {
    unsigned int w0 = g[(size_t)csr[start + j] * HID2 + lane];
    acc += __uint_as_float(w0 << 16);
  }
  float dg = fmaxf((float)d, 1.0f);
  unsigned int rw = r[(size_t)node * HID2 + lane];
  float v = fmaxf(acc / dg + __uint_as_float(rw << 16), 0.0f);
  float p0 = v * wc[lane * 2 + 0];
  float p1 = v * wc[lane * 2 + 1];
#pragma unroll
  for (int o2 = 16; o2 > 0; o2 >>= 1) {
    p0 += __shfl_down(p0, o2, 32);
    p1 += __shfl_down(p1, o2, 32);
  }
  if (lane == 0) {
    out[(size_t)node * 2 + 0] = p0 + bc[0];
    out[(size_t)node * 2 + 1] = p1 + bc[1];
  }
}

extern "C" void kernel_launch(void* const* d_in, const int* in_sizes, int n_in,
                              void* d_out, int out_size, void* d_ws, size_t ws_size,
                              hipStream_t stream) {
  const float* x   = (const float*)d_in[0];
  const int*   ei  = (const int*)d_in[1];
  const float* w1l = (const float*)d_in[2];
  const float* b1  = (const float*)d_in[3];
  const float* w1r = (const float*)d_in[4];
  const float* w2l = (const float*)d_in[5];
  const float* b2  = (const float*)d_in[6];
  const float* w2r = (const float*)d_in[7];
  const float* wc  = (const float*)d_in[8];
  const float* bc  = (const float*)d_in[9];
  float* out = (float*)d_out;

  int N = in_sizes[0] / IN_CH;
  int E = in_sizes[1] / 2;

  // ws (ints): deg[N] off[N] bsums[2048] flagpad[4] csr[E]  — csr 16B-aligned
  // then: epos[E] u16 | in_bf[N*32] u16 (16B-aligned) | g[N*32] u16 | r[N*32] u16 | wfrag[3072] u32
  int* deg   = (int*)d_ws;
  int* off   = deg + N;
  int* bsums = off + N;
  int* flag  = bsums + 2048;
  int* csr   = flag + 4;
  unsigned short* epos = (unsigned short*)(csr + E);
  unsigned int*   inb32 = (unsigned int*)(epos + E);
  unsigned short* inb   = (unsigned short*)inb32;
  unsigned short* g    = (unsigned short*)(inb32 + (size_t)N * 16);
  unsigned short* r    = g + (size_t)N * HID2;
  unsigned int*  wfrag = (unsigned int*)(r + (size_t)N * HID2);

  hipMemsetAsync(deg, 0, sizeof(int) * (size_t)N, stream);
  detect_i64<<<1, 64, 0, stream>>>(ei, flag);

  int e2blocks = ((E + 1) / 2 + 255) / 256;
  count_pos<<<e2blocks, 256, 0, stream>>>(ei, deg, epos, flag, E);

  xcast<<<((size_t)N * 8 + 255) / 256, 256, 0, stream>>>(x, inb32, N);
  prep_frags<<<12, 64, 0, stream>>>(w1l, w1r, w2l, w2r, wfrag);

  int P = (N + SCAN_EPB - 1) / SCAN_EPB;
  scan1<<<P, SCAN_BS, 0, stream>>>(deg, off, bsums, N);
  scan2<<<1, SCAN_BS, 0, stream>>>(bsums, P);
  scan3<<<(N + 255) / 256, 256, 0, stream>>>(off, bsums, N);

  scatter_edges<<<e2blocks, 256, 0, stream>>>(ei, off, epos, csr, flag, E);

  agg1_mean<<<((size_t)N * 8 + 255) / 256, 256, 0, stream>>>(off, deg, csr, inb32, N);

  layer1_mfma<<<1024, 256, 0, stream>>>(inb, wfrag, b1, b2, g, r, N);

  agg2_final<<<((size_t)N * 32 + 255) / 256, 256, 0, stream>>>(
      off, deg, csr, g, r, wc, bc, out, N);
}

// Round 9
// 384.734 us; speedup vs baseline: 3.9018x; 1.3604x over previous
//
#include <hip/hip_runtime.h>
#include <hip/hip_bf16.h>

// FraudGraphSAGE: 2-layer GraphSAGE (mean agg) + linear classifier.
// N=200000 nodes (12ch), E=3.2M edges.
//
// R8: binned CSR build — replaces 3.2M global return-atomics (count_pos) +
// 3.2M random 4B writes (scatter) with:
//   p1_hist  : LDS bucket histogram (bucket = dst>>10), ~76K fire-forget atomics
//   scan_b   : scan 196 bucket totals -> bstart/bcur
//   p2_bin   : per-block chunk reservation + packed (dstl<<18|src) u32 writes,
//              bucket-contiguous (sequential-ish, no line amplification)
//   p3_build : 1 block/bucket, 1024 thr: LDS count+scan+pos -> csr/deg/off
// layer1 stays MFMA (R6), agg1/agg2 gathers unchanged.

#define IN_CH 12
#define HID   64
#define HID2  32

using f32x4  = __attribute__((ext_vector_type(4))) float;
using bf16x8 = __attribute__((ext_vector_type(8))) short;

__device__ __forceinline__ unsigned short f2bf(float f) {
  union { float f; unsigned int u; } cv; cv.f = f;
  unsigned int b = cv.u;
  return (unsigned short)((b + 0x7fffu + ((b >> 16) & 1u)) >> 16);
}
__device__ __forceinline__ unsigned int packbf(float a, float b) {
  return (unsigned int)f2bf(a) | ((unsigned int)f2bf(b) << 16);
}

__global__ void detect_i64(const int* __restrict__ ei, int* __restrict__ flag) {
  if ((blockIdx.x | threadIdx.x) == 0) {
    *flag = ((ei[1] | ei[3] | ei[5] | ei[7]) == 0) ? 1 : 0;
  }
}

// 8192 edges/block; LDS histogram of dst buckets; one global atomic per
// (block,bucket). Fire-and-forget (no return value used).
__global__ __launch_bounds__(256) void p1_hist(
    const int* __restrict__ ei, int* __restrict__ bcnt,
    const int* __restrict__ flag, int E, int nb) {
  __shared__ int lh[256];
  int t = threadIdx.x;
  lh[t] = 0;
  __syncthreads();
  int f64 = *flag;
  size_t base = (size_t)blockIdx.x * 8192;
  for (int i = 0; i < 32; ++i) {
    size_t e = base + (size_t)i * 256 + t;
    if (e < (size_t)E) {
      int dst = f64 ? ei[2 * ((size_t)E + e)] : ei[(size_t)E + e];
      atomicAdd(&lh[dst >> 10], 1);
    }
  }
  __syncthreads();
  if (t < nb && lh[t]) atomicAdd(&bcnt[t], lh[t]);
}

__global__ __launch_bounds__(256) void scan_buckets(
    const int* __restrict__ bcnt, int* __restrict__ bstart,
    int* __restrict__ bcur, int nb) {
  __shared__ int s[256];
  int t = threadIdx.x;
  int v = (t < nb) ? bcnt[t] : 0;
  s[t] = v;
  __syncthreads();
  for (int d = 1; d < 256; d <<= 1) {
    int a = (t >= d) ? s[t - d] : 0;
    __syncthreads();
    s[t] += a;
    __syncthreads();
  }
  int excl = s[t] - v;
  if (t < nb) { bstart[t] = excl; bcur[t] = excl; }
  if (t == 255) bstart[nb] = s[255];
}

// Reserve per-(block,bucket) chunks, then write packed edges bucket-major.
// pack = (dst&1023)<<18 | src  (requires N < 2^18 = 262144; here N=200000).
__global__ __launch_bounds__(256) void p2_bin(
    const int* __restrict__ ei, int* __restrict__ bcur,
    unsigned int* __restrict__ binned, const int* __restrict__ flag,
    int E, int nb) {
  __shared__ int lh[256];
  __shared__ int lbase[256];
  int t = threadIdx.x;
  lh[t] = 0;
  __syncthreads();
  int f64 = *flag;
  size_t base = (size_t)blockIdx.x * 8192;
  for (int i = 0; i < 32; ++i) {
    size_t e = base + (size_t)i * 256 + t;
    if (e < (size_t)E) {
      int dst = f64 ? ei[2 * ((size_t)E + e)] : ei[(size_t)E + e];
      atomicAdd(&lh[dst >> 10], 1);
    }
  }
  __syncthreads();
  if (t < nb) {
    int c = lh[t];
    lbase[t] = c ? atomicAdd(&bcur[t], c) : 0;
  }
  __syncthreads();
  lh[t] = 0;
  __syncthreads();
  for (int i = 0; i < 32; ++i) {
    size_t e = base + (size_t)i * 256 + t;
    if (e < (size_t)E) {
      int src, dst;
      if (f64) { src = ei[2 * e]; dst = ei[2 * ((size_t)E + e)]; }
      else     { src = ei[e];     dst = ei[(size_t)E + e]; }
      int b = dst >> 10;
      int lp = atomicAdd(&lh[b], 1);
      binned[lbase[b] + lp] = ((unsigned int)(dst & 1023) << 18) | (unsigned int)src;
    }
  }
}

// One block per bucket (<=1024 nodes). LDS count -> scan -> position atomics.
// Emits csr (bucket window, L2-resident), deg, off.
__global__ __launch_bounds__(1024) void p3_build(
    const unsigned int* __restrict__ binned, const int* __restrict__ bstart,
    int* __restrict__ deg, int* __restrict__ off, int* __restrict__ csr, int N) {
  __shared__ int cnt[1024];
  __shared__ int s[1024];
  __shared__ int cur[1024];
  int t = threadIdx.x;
  int b = blockIdx.x;
  int nbase = b << 10;
  int estart = bstart[b], eend = bstart[b + 1];
  cnt[t] = 0;
  __syncthreads();
  for (int e = estart + t; e < eend; e += 1024) {
    unsigned int p = binned[e];
    atomicAdd(&cnt[p >> 18], 1);
  }
  __syncthreads();
  int v = cnt[t];
  s[t] = v;
  __syncthreads();
  for (int d = 1; d < 1024; d <<= 1) {
    int a = (t >= d) ? s[t - d] : 0;
    __syncthreads();
    s[t] += a;
    __syncthreads();
  }
  int excl = s[t] - v;
  int node = nbase + t;
  if (node < N) { deg[node] = v; off[node] = estart + excl; }
  cur[t] = estart + excl;
  __syncthreads();
  for (int e = estart + t; e < eend; e += 1024) {
    unsigned int p = binned[e];
    int pos = atomicAdd(&cur[p >> 18], 1);
    csr[pos] = (int)(p & 0x3FFFFu);
  }
}

// Writes x-half of in_bf: u32 slots 8..15 of each 16-u32 row.
__global__ __launch_bounds__(256) void xcast(
    const float* __restrict__ x, unsigned int* __restrict__ inb32, int N) {
  int i = blockIdx.x * 256 + threadIdx.x;
  if (i >= N * 8) return;
  int n = i >> 3, cp = i & 7;
  unsigned int w = 0;
  if (cp < 6) {
    float2 v = *(const float2*)(x + (size_t)n * IN_CH + cp * 2);
    w = packbf(v.x, v.y);
  }
  inb32[(size_t)n * 16 + 8 + cp] = w;
}

// Gathers neighbor x (bf16) and writes bf16 MEAN into slots 0..7.
__global__ __launch_bounds__(256) void agg1_mean(
    const int* __restrict__ off, const int* __restrict__ deg,
    const int* __restrict__ csr, unsigned int* __restrict__ inb32, int N) {
  int tid = blockIdx.x * 256 + threadIdx.x;
  int node = tid >> 3;
  int l = tid & 7;
  if (node >= N) return;
  unsigned int* row = inb32 + (size_t)node * 16;
  if (l >= 6) { row[l] = 0; return; }
  int start = off[node], d = deg[node];
  float a0 = 0.f, a1 = 0.f;
  int j = 0;
  for (; j + 1 < d; j += 2) {
    int s0 = csr[start + j], s1 = csr[start + j + 1];
    unsigned int w0 = inb32[(size_t)s0 * 16 + 8 + l];
    unsigned int w1 = inb32[(size_t)s1 * 16 + 8 + l];
    a0 += __uint_as_float(w0 << 16) + __uint_as_float(w1 << 16);
    a1 += __uint_as_float(w0 & 0xffff0000u) + __uint_as_float(w1 & 0xffff0000u);
  }
  if (j < d) {
    unsigned int w0 = inb32[(size_t)csr[start + j] * 16 + 8 + l];
    a0 += __uint_as_float(w0 << 16);
    a1 += __uint_as_float(w0 & 0xffff0000u);
  }
  float inv = 1.0f / fmaxf((float)d, 1.0f);
  row[l] = packbf(a0 * inv, a1 * inv);
}

// Prepack weight fragments (A-operand, transposed orientation).
__global__ void prep_frags(
    const float* __restrict__ w1l, const float* __restrict__ w1r,
    const float* __restrict__ w2l, const float* __restrict__ w2r,
    unsigned int* __restrict__ wfrag) {
  int f = blockIdx.x, l = threadIdx.x;
  int q = l >> 4, c = l & 15;
  unsigned int out[4];
#pragma unroll
  for (int p = 0; p < 4; ++p) {
    float v[2];
#pragma unroll
    for (int s = 0; s < 2; ++s) {
      int i = 2 * p + s;
      float val = 0.f;
      if (f < 4) {
        int k = q * 8 + i, ch = f * 16 + c;
        if (k < 12) val = w1l[k * HID + ch];
        else if (k >= 16 && k < 28) val = w1r[(k - 16) * HID + ch];
      } else {
        int t2 = (f - 4) >> 1, half = (f - 4) & 1;
        int k = half * 32 + q * 8 + i;
        int oc = t2 * 16 + c;
        val = (t2 < 2) ? w2l[k * HID2 + oc] : w2r[k * HID2 + (oc - 32)];
      }
      v[s] = val;
    }
    out[p] = packbf(v[0], v[1]);
  }
  *(uint4*)&wfrag[(f * 64 + l) * 4] = make_uint4(out[0], out[1], out[2], out[3]);
}

// MFMA layer1 (R6): per wave one 16-node tile per pass.
__global__ __launch_bounds__(256) void layer1_mfma(
    const unsigned short* __restrict__ in_bf, const unsigned int* __restrict__ wfrag,
    const float* __restrict__ b1, const float* __restrict__ b2,
    unsigned short* __restrict__ g, unsigned short* __restrict__ r, int N) {
  __shared__ unsigned int s_h[4][512];
  int t = threadIdx.x, wave = t >> 6, l = t & 63;
  int q = l >> 4, c = l & 15;
  int swz = c & 7;

  union FU { uint4 u4; bf16x8 v; } fu;
  bf16x8 a1[4], a2[8];
#pragma unroll
  for (int f = 0; f < 4; ++f) { fu.u4 = ((const uint4*)wfrag)[f * 64 + l]; a1[f] = fu.v; }
#pragma unroll
  for (int f = 0; f < 8; ++f) { fu.u4 = ((const uint4*)wfrag)[(4 + f) * 64 + l]; a2[f] = fu.v; }

  f32x4 c1[4], c2[4];
#pragma unroll
  for (int t1 = 0; t1 < 4; ++t1) {
    float4 bv = *(const float4*)(b1 + t1 * 16 + q * 4);
    c1[t1][0] = bv.x; c1[t1][1] = bv.y; c1[t1][2] = bv.z; c1[t1][3] = bv.w;
  }
#pragma unroll
  for (int t2 = 0; t2 < 4; ++t2) {
    if (t2 < 2) { c2[t2][0] = 0.f; c2[t2][1] = 0.f; c2[t2][2] = 0.f; c2[t2][3] = 0.f; }
    else {
      float4 bv = *(const float4*)(b2 + (t2 - 2) * 16 + q * 4);
      c2[t2][0] = bv.x; c2[t2][1] = bv.y; c2[t2][2] = bv.z; c2[t2][3] = bv.w;
    }
  }

  int ntiles = (N + 15) >> 4;
  for (int tile = blockIdx.x * 4 + wave; tile < ntiles; tile += gridDim.x * 4) {
    int node_g = tile * 16 + c;
    int ng = node_g < N ? node_g : N - 1;
    fu.u4 = ((const uint4*)in_bf)[(size_t)ng * 4 + q];
    bf16x8 bfrag = fu.v;

#pragma unroll
    for (int t1 = 0; t1 < 4; ++t1) {
      f32x4 d = __builtin_amdgcn_mfma_f32_16x16x32_bf16(a1[t1], bfrag, c1[t1], 0, 0, 0);
      unsigned int lo = packbf(fmaxf(d[0], 0.f), fmaxf(d[1], 0.f));
      unsigned int hi = packbf(fmaxf(d[2], 0.f), fmaxf(d[3], 0.f));
      int gr = (t1 * 2 + (q >> 1)) ^ swz;
      int idx = c * 32 + gr * 4 + (q & 1) * 2;
      *(uint2*)&s_h[wave][idx] = make_uint2(lo, hi);
    }
    __builtin_amdgcn_wave_barrier();

    bf16x8 hf0, hf1;
    fu.u4 = *(const uint4*)&s_h[wave][c * 32 + ((q) ^ swz) * 4];       hf0 = fu.v;
    fu.u4 = *(const uint4*)&s_h[wave][c * 32 + ((4 + q) ^ swz) * 4];   hf1 = fu.v;

    if (node_g < N) {
      size_t gb = (size_t)node_g * HID2;
#pragma unroll
      for (int t2 = 0; t2 < 4; ++t2) {
        f32x4 d = __builtin_amdgcn_mfma_f32_16x16x32_bf16(a2[t2 * 2 + 0], hf0, c2[t2], 0, 0, 0);
        d = __builtin_amdgcn_mfma_f32_16x16x32_bf16(a2[t2 * 2 + 1], hf1, d, 0, 0, 0);
        unsigned int lo = packbf(d[0], d[1]);
        unsigned int hi = packbf(d[2], d[3]);
        unsigned short* dst = (t2 < 2) ? g : r;
        int ch = (t2 & 1) * 16 + q * 4;
        *(uint2*)(dst + gb + ch) = make_uint2(lo, hi);
      }
    }
    __builtin_amdgcn_wave_barrier();
  }
}

__global__ __launch_bounds__(256) void agg2_final(
    const int* __restrict__ off, const int* __restrict__ deg,
    const int* __restrict__ csr, const unsigned short* __restrict__ g,
    const unsigned short* __restrict__ r, const float* __restrict__ wc,
    const float* __restrict__ bc, float* __restrict__ out, int N) {
  int tid = blockIdx.x * 256 + threadIdx.x;
  int node = tid >> 5;
  int lane = tid & 31;
  if (node >= N) return;
  int start = off[node], d = deg[node];
  float acc = 0.f;
  int j = 0;
  for (; j + 1 < d; j += 2) {
    int s0 = csr[start + j], s1 = csr[start + j + 1];
    unsigned int w0 = g[(size_t)s0 * HID2 + lane];
    unsigned int w1 = g[(size_t)s1 * HID2 + lane];
    acc += __uint_as_float(w0 << 16) + __uint_as_float(w1 << 16);
  }
  if (j < d) {
    unsigned int w0 = g[(size_t)csr[start + j] * HID2 + lane];
    acc += __uint_as_float(w0 << 16);
  }
  float dg = fmaxf((float)d, 1.0f);
  unsigned int rw = r[(size_t)node * HID2 + lane];
  float v = fmaxf(acc / dg + __uint_as_float(rw << 16), 0.0f);
  float p0 = v * wc[lane * 2 + 0];
  float p1 = v * wc[lane * 2 + 1];
#pragma unroll
  for (int o2 = 16; o2 > 0; o2 >>= 1) {
    p0 += __shfl_down(p0, o2, 32);
    p1 += __shfl_down(p1, o2, 32);
  }
  if (lane == 0) {
    out[(size_t)node * 2 + 0] = p0 + bc[0];
    out[(size_t)node * 2 + 1] = p1 + bc[1];
  }
}

extern "C" void kernel_launch(void* const* d_in, const int* in_sizes, int n_in,
                              void* d_out, int out_size, void* d_ws, size_t ws_size,
                              hipStream_t stream) {
  const float* x   = (const float*)d_in[0];
  const int*   ei  = (const int*)d_in[1];
  const float* w1l = (const float*)d_in[2];
  const float* b1  = (const float*)d_in[3];
  const float* w1r = (const float*)d_in[4];
  const float* w2l = (const float*)d_in[5];
  const float* b2  = (const float*)d_in[6];
  const float* w2r = (const float*)d_in[7];
  const float* wc  = (const float*)d_in[8];
  const float* bc  = (const float*)d_in[9];
  float* out = (float*)d_out;

  int N = in_sizes[0] / IN_CH;
  int E = in_sizes[1] / 2;
  int nb = (N + 1023) >> 10;  // 196 buckets

  // ws ints: deg[N] off[N] bmeta[772] csr[E] binned[E]
  //   bmeta: bcnt=+0(256), bstart=+256(257), bcur=+513(256), flag=+769, pad 770..771
  // then u32 inb32[N*16] | u16 g[N*32] r[N*32] | u32 wfrag[3072]  (~66 MB)
  int* deg    = (int*)d_ws;
  int* off    = deg + N;
  int* bmeta  = off + N;
  int* bcnt   = bmeta;
  int* bstart = bmeta + 256;
  int* bcur   = bmeta + 513;
  int* flag   = bmeta + 769;
  int* csr    = bmeta + 772;
  unsigned int* binned = (unsigned int*)(csr + E);
  unsigned int* inb32  = binned + E;
  unsigned short* inb  = (unsigned short*)inb32;
  unsigned short* g    = (unsigned short*)(inb32 + (size_t)N * 16);
  unsigned short* r    = g + (size_t)N * HID2;
  unsigned int* wfrag  = (unsigned int*)(r + (size_t)N * HID2);

  hipMemsetAsync(bcnt, 0, 256 * sizeof(int), stream);
  detect_i64<<<1, 64, 0, stream>>>(ei, flag);

  xcast<<<((size_t)N * 8 + 255) / 256, 256, 0, stream>>>(x, inb32, N);
  prep_frags<<<12, 64, 0, stream>>>(w1l, w1r, w2l, w2r, wfrag);

  int ebblocks = (E + 8191) / 8192;
  p1_hist<<<ebblocks, 256, 0, stream>>>(ei, bcnt, flag, E, nb);
  scan_buckets<<<1, 256, 0, stream>>>(bcnt, bstart, bcur, nb);
  p2_bin<<<ebblocks, 256, 0, stream>>>(ei, bcur, binned, flag, E, nb);
  p3_build<<<nb, 1024, 0, stream>>>(binned, bstart, deg, off, csr, N);

  agg1_mean<<<((size_t)N * 8 + 255) / 256, 256, 0, stream>>>(off, deg, csr, inb32, N);

  layer1_mfma<<<1024, 256, 0, stream>>>(inb, wfrag, b1, b2, g, r, N);

  agg2_final<<<((size_t)N * 32 + 255) / 256, 256, 0, stream>>>(
      off, deg, csr, g, r, wc, bc, out, N);
}

// Round 11
// 342.252 us; speedup vs baseline: 4.3861x; 1.1241x over previous
//
#include <hip/hip_runtime.h>
#include <hip/hip_bf16.h>

// FraudGraphSAGE: 2-layer GraphSAGE (mean agg) + linear classifier.
// N=200000 nodes (12ch), E=3.2M edges.
//
// R10: gather ILP fix. R9 showed agg2_final latency-bound (VGPR=12 -> ~2
// loads in flight; 2.17 TB/s << fetch-path BW). Both gather kernels now do
// 8-deep batched loads (clamped-index, cndmask-zero: no scalar tail).
// Everything else = R8 (binned CSR build + MFMA layer1).

#define IN_CH 12
#define HID   64
#define HID2  32

using f32x4  = __attribute__((ext_vector_type(4))) float;
using bf16x8 = __attribute__((ext_vector_type(8))) short;

__device__ __forceinline__ unsigned short f2bf(float f) {
  union { float f; unsigned int u; } cv; cv.f = f;
  unsigned int b = cv.u;
  return (unsigned short)((b + 0x7fffu + ((b >> 16) & 1u)) >> 16);
}
__device__ __forceinline__ unsigned int packbf(float a, float b) {
  return (unsigned int)f2bf(a) | ((unsigned int)f2bf(b) << 16);
}

__global__ void detect_i64(const int* __restrict__ ei, int* __restrict__ flag) {
  if ((blockIdx.x | threadIdx.x) == 0) {
    *flag = ((ei[1] | ei[3] | ei[5] | ei[7]) == 0) ? 1 : 0;
  }
}

// 8192 edges/block; LDS histogram of dst buckets; one global atomic per
// (block,bucket). Fire-and-forget.
__global__ __launch_bounds__(256) void p1_hist(
    const int* __restrict__ ei, int* __restrict__ bcnt,
    const int* __restrict__ flag, int E, int nb) {
  __shared__ int lh[256];
  int t = threadIdx.x;
  lh[t] = 0;
  __syncthreads();
  int f64 = *flag;
  size_t base = (size_t)blockIdx.x * 8192;
  for (int i = 0; i < 32; ++i) {
    size_t e = base + (size_t)i * 256 + t;
    if (e < (size_t)E) {
      int dst = f64 ? ei[2 * ((size_t)E + e)] : ei[(size_t)E + e];
      atomicAdd(&lh[dst >> 10], 1);
    }
  }
  __syncthreads();
  if (t < nb && lh[t]) atomicAdd(&bcnt[t], lh[t]);
}

__global__ __launch_bounds__(256) void scan_buckets(
    const int* __restrict__ bcnt, int* __restrict__ bstart,
    int* __restrict__ bcur, int nb) {
  __shared__ int s[256];
  int t = threadIdx.x;
  int v = (t < nb) ? bcnt[t] : 0;
  s[t] = v;
  __syncthreads();
  for (int d = 1; d < 256; d <<= 1) {
    int a = (t >= d) ? s[t - d] : 0;
    __syncthreads();
    s[t] += a;
    __syncthreads();
  }
  int excl = s[t] - v;
  if (t < nb) { bstart[t] = excl; bcur[t] = excl; }
  if (t == 255) bstart[nb] = s[255];
}

// Reserve per-(block,bucket) chunks, then write packed edges bucket-major.
// pack = (dst&1023)<<18 | src  (requires N < 2^18; here N=200000).
__global__ __launch_bounds__(256) void p2_bin(
    const int* __restrict__ ei, int* __restrict__ bcur,
    unsigned int* __restrict__ binned, const int* __restrict__ flag,
    int E, int nb) {
  __shared__ int lh[256];
  __shared__ int lbase[256];
  int t = threadIdx.x;
  lh[t] = 0;
  __syncthreads();
  int f64 = *flag;
  size_t base = (size_t)blockIdx.x * 8192;
  for (int i = 0; i < 32; ++i) {
    size_t e = base + (size_t)i * 256 + t;
    if (e < (size_t)E) {
      int dst = f64 ? ei[2 * ((size_t)E + e)] : ei[(size_t)E + e];
      atomicAdd(&lh[dst >> 10], 1);
    }
  }
  __syncthreads();
  if (t < nb) {
    int c = lh[t];
    lbase[t] = c ? atomicAdd(&bcur[t], c) : 0;
  }
  __syncthreads();
  lh[t] = 0;
  __syncthreads();
  for (int i = 0; i < 32; ++i) {
    size_t e = base + (size_t)i * 256 + t;
    if (e < (size_t)E) {
      int src, dst;
      if (f64) { src = ei[2 * e]; dst = ei[2 * ((size_t)E + e)]; }
      else     { src = ei[e];     dst = ei[(size_t)E + e]; }
      int b = dst >> 10;
      int lp = atomicAdd(&lh[b], 1);
      binned[lbase[b] + lp] = ((unsigned int)(dst & 1023) << 18) | (unsigned int)src;
    }
  }
}

// One block per bucket (<=1024 nodes). LDS count -> scan -> position atomics.
__global__ __launch_bounds__(1024) void p3_build(
    const unsigned int* __restrict__ binned, const int* __restrict__ bstart,
    int* __restrict__ deg, int* __restrict__ off, int* __restrict__ csr, int N) {
  __shared__ int cnt[1024];
  __shared__ int s[1024];
  __shared__ int cur[1024];
  int t = threadIdx.x;
  int b = blockIdx.x;
  int nbase = b << 10;
  int estart = bstart[b], eend = bstart[b + 1];
  cnt[t] = 0;
  __syncthreads();
  for (int e = estart + t; e < eend; e += 1024) {
    unsigned int p = binned[e];
    atomicAdd(&cnt[p >> 18], 1);
  }
  __syncthreads();
  int v = cnt[t];
  s[t] = v;
  __syncthreads();
  for (int d = 1; d < 1024; d <<= 1) {
    int a = (t >= d) ? s[t - d] : 0;
    __syncthreads();
    s[t] += a;
    __syncthreads();
  }
  int excl = s[t] - v;
  int node = nbase + t;
  if (node < N) { deg[node] = v; off[node] = estart + excl; }
  cur[t] = estart + excl;
  __syncthreads();
  for (int e = estart + t; e < eend; e += 1024) {
    unsigned int p = binned[e];
    int pos = atomicAdd(&cur[p >> 18], 1);
    csr[pos] = (int)(p & 0x3FFFFu);
  }
}

// Writes x-half of in_bf: u32 slots 8..15 of each 16-u32 row.
__global__ __launch_bounds__(256) void xcast(
    const float* __restrict__ x, unsigned int* __restrict__ inb32, int N) {
  int i = blockIdx.x * 256 + threadIdx.x;
  if (i >= N * 8) return;
  int n = i >> 3, cp = i & 7;
  unsigned int w = 0;
  if (cp < 6) {
    float2 v = *(const float2*)(x + (size_t)n * IN_CH + cp * 2);
    w = packbf(v.x, v.y);
  }
  inb32[(size_t)n * 16 + 8 + cp] = w;
}

// Gathers neighbor x (bf16) with 8-deep ILP; writes bf16 MEAN into slots 0..7.
__global__ __launch_bounds__(256) void agg1_mean(
    const int* __restrict__ off, const int* __restrict__ deg,
    const int* __restrict__ csr, unsigned int* __restrict__ inb32, int N) {
  int tid = blockIdx.x * 256 + threadIdx.x;
  int node = tid >> 3;
  int l = tid & 7;
  if (node >= N) return;
  unsigned int* row = inb32 + (size_t)node * 16;
  if (l >= 6) { row[l] = 0; return; }
  int start = off[node], d = deg[node];
  const unsigned int* xg = inb32 + 8 + l;
  float a0 = 0.f, a1 = 0.f;
  for (int j = 0; j < d; j += 8) {
    unsigned int w[8];
#pragma unroll
    for (int k = 0; k < 8; ++k) {
      int jj = j + k;
      int s = csr[start + (jj < d ? jj : 0)];
      unsigned int wv = xg[(size_t)s * 16];
      w[k] = (jj < d) ? wv : 0u;
    }
#pragma unroll
    for (int k = 0; k < 8; ++k) {
      a0 += __uint_as_float(w[k] << 16);
      a1 += __uint_as_float(w[k] & 0xffff0000u);
    }
  }
  float inv = 1.0f / fmaxf((float)d, 1.0f);
  row[l] = packbf(a0 * inv, a1 * inv);
}

// Prepack weight fragments (A-operand, transposed orientation).
__global__ void prep_frags(
    const float* __restrict__ w1l, const float* __restrict__ w1r,
    const float* __restrict__ w2l, const float* __restrict__ w2r,
    unsigned int* __restrict__ wfrag) {
  int f = blockIdx.x, l = threadIdx.x;
  int q = l >> 4, c = l & 15;
  unsigned int out[4];
#pragma unroll
  for (int p = 0; p < 4; ++p) {
    float v[2];
#pragma unroll
    for (int s = 0; s < 2; ++s) {
      int i = 2 * p + s;
      float val = 0.f;
      if (f < 4) {
        int k = q * 8 + i, ch = f * 16 + c;
        if (k < 12) val = w1l[k * HID + ch];
        else if (k >= 16 && k < 28) val = w1r[(k - 16) * HID + ch];
      } else {
        int t2 = (f - 4) >> 1, half = (f - 4) & 1;
        int k = half * 32 + q * 8 + i;
        int oc = t2 * 16 + c;
        val = (t2 < 2) ? w2l[k * HID2 + oc] : w2r[k * HID2 + (oc - 32)];
      }
      v[s] = val;
    }
    out[p] = packbf(v[0], v[1]);
  }
  *(uint4*)&wfrag[(f * 64 + l) * 4] = make_uint4(out[0], out[1], out[2], out[3]);
}

// MFMA layer1 (R6): per wave one 16-node tile per pass.
__global__ __launch_bounds__(256) void layer1_mfma(
    const unsigned short* __restrict__ in_bf, const unsigned int* __restrict__ wfrag,
    const float* __restrict__ b1, const float* __restrict__ b2,
    unsigned short* __restrict__ g, unsigned short* __restrict__ r, int N) {
  __shared__ unsigned int s_h[4][512];
  int t = threadIdx.x, wave = t >> 6, l = t & 63;
  int q = l >> 4, c = l & 15;
  int swz = c & 7;

  union FU { uint4 u4; bf16x8 v; } fu;
  bf16x8 a1[4], a2[8];
#pragma unroll
  for (int f = 0; f < 4; ++f) { fu.u4 = ((const uint4*)wfrag)[f * 64 + l]; a1[f] = fu.v; }
#pragma unroll
  for (int f = 0; f < 8; ++f) { fu.u4 = ((const uint4*)wfrag)[(4 + f) * 64 + l]; a2[f] = fu.v; }

  f32x4 c1[4], c2[4];
#pragma unroll
  for (int t1 = 0; t1 < 4; ++t1) {
    float4 bv = *(const float4*)(b1 + t1 * 16 + q * 4);
    c1[t1][0] = bv.x; c1[t1][1] = bv.y; c1[t1][2] = bv.z; c1[t1][3] = bv.w;
  }
#pragma unroll
  for (int t2 = 0; t2 < 4; ++t2) {
    if (t2 < 2) { c2[t2][0] = 0.f; c2[t2][1] = 0.f; c2[t2][2] = 0.f; c2[t2][3] = 0.f; }
    else {
      float4 bv = *(const float4*)(b2 + (t2 - 2) * 16 + q * 4);
      c2[t2][0] = bv.x; c2[t2][1] = bv.y; c2[t2][2] = bv.z; c2[t2][3] = bv.w;
    }
  }

  int ntiles = (N + 15) >> 4;
  for (int tile = blockIdx.x * 4 + wave; tile < ntiles; tile += gridDim.x * 4) {
    int node_g = tile * 16 + c;
    int ng = node_g < N ? node_g : N - 1;
    fu.u4 = ((const uint4*)in_bf)[(size_t)ng * 4 + q];
    bf16x8 bfrag = fu.v;

#pragma unroll
    for (int t1 = 0; t1 < 4; ++t1) {
      f32x4 d = __builtin_amdgcn_mfma_f32_16x16x32_bf16(a1[t1], bfrag, c1[t1], 0, 0, 0);
      unsigned int lo = packbf(fmaxf(d[0], 0.f), fmaxf(d[1], 0.f));
      unsigned int hi = packbf(fmaxf(d[2], 0.f), fmaxf(d[3], 0.f));
      int gr = (t1 * 2 + (q >> 1)) ^ swz;
      int idx = c * 32 + gr * 4 + (q & 1) * 2;
      *(uint2*)&s_h[wave][idx] = make_uint2(lo, hi);
    }
    __builtin_amdgcn_wave_barrier();

    bf16x8 hf0, hf1;
    fu.u4 = *(const uint4*)&s_h[wave][c * 32 + ((q) ^ swz) * 4];       hf0 = fu.v;
    fu.u4 = *(const uint4*)&s_h[wave][c * 32 + ((4 + q) ^ swz) * 4];   hf1 = fu.v;

    if (node_g < N) {
      size_t gb = (size_t)node_g * HID2;
#pragma unroll
      for (int t2 = 0; t2 < 4; ++t2) {
        f32x4 d = __builtin_amdgcn_mfma_f32_16x16x32_bf16(a2[t2 * 2 + 0], hf0, c2[t2], 0, 0, 0);
        d = __builtin_amdgcn_mfma_f32_16x16x32_bf16(a2[t2 * 2 + 1], hf1, d, 0, 0, 0);
        unsigned int lo = packbf(d[0], d[1]);
        unsigned int hi = packbf(d[2], d[3]);
        unsigned short* dst = (t2 < 2) ? g : r;
        int ch = (t2 & 1) * 16 + q * 4;
        *(uint2*)(dst + gb + ch) = make_uint2(lo, hi);
      }
    }
    __builtin_amdgcn_wave_barrier();
  }
}

// 8-deep-ILP gather of g rows + classifier.
__global__ __launch_bounds__(256) void agg2_final(
    const int* __restrict__ off, const int* __restrict__ deg,
    const int* __restrict__ csr, const unsigned short* __restrict__ g,
    const unsigned short* __restrict__ r, const float* __restrict__ wc,
    const float* __restrict__ bc, float* __restrict__ out, int N) {
  int tid = blockIdx.x * 256 + threadIdx.x;
  int node = tid >> 5;
  int lane = tid & 31;
  if (node >= N) return;
  int start = off[node], d = deg[node];
  const unsigned short* gl = g + lane;
  float acc = 0.f;
  for (int j = 0; j < d; j += 8) {
    unsigned int w[8];
#pragma unroll
    for (int k = 0; k < 8; ++k) {
      int jj = j + k;
      int s = csr[start + (jj < d ? jj : 0)];
      unsigned int wv = (unsigned int)gl[(size_t)s * HID2];
      w[k] = (jj < d) ? wv : 0u;
    }
#pragma unroll
    for (int k = 0; k < 8; ++k) acc += __uint_as_float(w[k] << 16);
  }
  float dg = fmaxf((float)d, 1.0f);
  unsigned int rw = r[(size_t)node * HID2 + lane];
  float v = fmaxf(acc / dg + __uint_as_float(rw << 16), 0.0f);
  float p0 = v * wc[lane * 2 + 0];
  float p1 = v * wc[lane * 2 + 1];
#pragma unroll
  for (int o2 = 16; o2 > 0; o2 >>= 1) {
    p0 += __shfl_down(p0, o2, 32);
    p1 += __shfl_down(p1, o2, 32);
  }
  if (lane == 0) {
    out[(size_t)node * 2 + 0] = p0 + bc[0];
    out[(size_t)node * 2 + 1] = p1 + bc[1];
  }
}

extern "C" void kernel_launch(void* const* d_in, const int* in_sizes, int n_in,
                              void* d_out, int out_size, void* d_ws, size_t ws_size,
                              hipStream_t stream) {
  const float* x   = (const float*)d_in[0];
  const int*   ei  = (const int*)d_in[1];
  const float* w1l = (const float*)d_in[2];
  const float* b1  = (const float*)d_in[3];
  const float* w1r = (const float*)d_in[4];
  const float* w2l = (const float*)d_in[5];
  const float* b2  = (const float*)d_in[6];
  const float* w2r = (const float*)d_in[7];
  const float* wc  = (const float*)d_in[8];
  const float* bc  = (const float*)d_in[9];
  float* out = (float*)d_out;

  int N = in_sizes[0] / IN_CH;
  int E = in_sizes[1] / 2;
  int nb = (N + 1023) >> 10;  // 196 buckets

  // ws ints: deg[N] off[N] bmeta[772] csr[E] binned[E]
  //   bmeta: bcnt=+0(256), bstart=+256(257), bcur=+513(256), flag=+769
  // then u32 inb32[N*16] | u16 g[N*32] r[N*32] | u32 wfrag[3072]
  int* deg    = (int*)d_ws;
  int* off    = deg + N;
  int* bmeta  = off + N;
  int* bcnt   = bmeta;
  int* bstart = bmeta + 256;
  int* bcur   = bmeta + 513;
  int* flag   = bmeta + 769;
  int* csr    = bmeta + 772;
  unsigned int* binned = (unsigned int*)(csr + E);
  unsigned int* inb32  = binned + E;
  unsigned short* inb  = (unsigned short*)inb32;
  unsigned short* g    = (unsigned short*)(inb32 + (size_t)N * 16);
  unsigned short* r    = g + (size_t)N * HID2;
  unsigned int* wfrag  = (unsigned int*)(r + (size_t)N * HID2);

  hipMemsetAsync(bcnt, 0, 256 * sizeof(int), stream);
  detect_i64<<<1, 64, 0, stream>>>(ei, flag);

  xcast<<<((size_t)N * 8 + 255) / 256, 256, 0, stream>>>(x, inb32, N);
  prep_frags<<<12, 64, 0, stream>>>(w1l, w1r, w2l, w2r, wfrag);

  int ebblocks = (E + 8191) / 8192;
  p1_hist<<<ebblocks, 256, 0, stream>>>(ei, bcnt, flag, E, nb);
  scan_buckets<<<1, 256, 0, stream>>>(bcnt, bstart, bcur, nb);
  p2_bin<<<ebblocks, 256, 0, stream>>>(ei, bcur, binned, flag, E, nb);
  p3_build<<<nb, 1024, 0, stream>>>(binned, bstart, deg, off, csr, N);

  agg1_mean<<<((size_t)N * 8 + 255) / 256, 256, 0, stream>>>(off, deg, csr, inb32, N);

  layer1_mfma<<<1024, 256, 0, stream>>>(inb, wfrag, b1, b2, g, r, N);

  agg2_final<<<((size_t)N * 32 + 255) / 256, 256, 0, stream>>>(
      off, deg, csr, g, r, wc, bc, out, N);
}

// Round 13
// 328.590 us; speedup vs baseline: 4.5685x; 1.0416x over previous
//
#include <hip/hip_runtime.h>
#include <hip/hip_bf16.h>

// FraudGraphSAGE: 2-layer GraphSAGE (mean agg) + linear classifier.
// N=200000 nodes (12ch), E=3.2M edges.
//
// R12: gather MLP fix + fusion.
//  - agg1: 4 lanes/node, uint2 loads -> 16 nodes/wave, 128 lines in flight
//  - agg2: 8 lanes/node, uint2 loads -> 8 nodes/wave, 64 lines in flight
//  - int64-detect inlined into edge kernels (no detect kernel, no flag dep)
//  - fused_pre = p1_hist + xcast + prep_frags in one launch (independent)
//  Rest = R8 binned CSR build + R6 MFMA layer1.

#define IN_CH 12
#define HID   64
#define HID2  32

using f32x4  = __attribute__((ext_vector_type(4))) float;
using bf16x8 = __attribute__((ext_vector_type(8))) short;

__device__ __forceinline__ unsigned short f2bf(float f) {
  union { float f; unsigned int u; } cv; cv.f = f;
  unsigned int b = cv.u;
  return (unsigned short)((b + 0x7fffu + ((b >> 16) & 1u)) >> 16);
}
__device__ __forceinline__ unsigned int packbf(float a, float b) {
  return (unsigned int)f2bf(a) | ((unsigned int)f2bf(b) << 16);
}
__device__ __forceinline__ int detect_f64(const int* __restrict__ ei) {
  return ((ei[1] | ei[3] | ei[5] | ei[7]) == 0) ? 1 : 0;
}

// Fused: [0,histB) = dst-bucket histogram; [histB,histB+xcastB) = xcast;
// [histB+xcastB, +12) = weight-fragment prepack.
__global__ __launch_bounds__(256) void fused_pre(
    const int* __restrict__ ei, int* __restrict__ bcnt,
    const float* __restrict__ x, unsigned int* __restrict__ inb32,
    const float* __restrict__ w1l, const float* __restrict__ w1r,
    const float* __restrict__ w2l, const float* __restrict__ w2r,
    unsigned int* __restrict__ wfrag, int E, int N, int nb,
    int histB, int xcastB) {
  int bid = blockIdx.x;
  int t = threadIdx.x;
  if (bid < histB) {
    __shared__ int lh[256];
    lh[t] = 0;
    __syncthreads();
    int f64 = detect_f64(ei);
    size_t base = (size_t)bid * 8192;
    for (int i = 0; i < 32; ++i) {
      size_t e = base + (size_t)i * 256 + t;
      if (e < (size_t)E) {
        int dst = f64 ? ei[2 * ((size_t)E + e)] : ei[(size_t)E + e];
        atomicAdd(&lh[dst >> 10], 1);
      }
    }
    __syncthreads();
    if (t < nb && lh[t]) atomicAdd(&bcnt[t], lh[t]);
  } else if (bid < histB + xcastB) {
    int i = (bid - histB) * 256 + t;
    if (i < N * 8) {
      int n = i >> 3, cp = i & 7;
      unsigned int w = 0;
      if (cp < 6) {
        float2 v = *(const float2*)(x + (size_t)n * IN_CH + cp * 2);
        w = packbf(v.x, v.y);
      }
      inb32[(size_t)n * 16 + 8 + cp] = w;
    }
  } else {
    if (t >= 64) return;
    int f = bid - histB - xcastB;
    int q = t >> 4, c = t & 15;
    unsigned int out[4];
#pragma unroll
    for (int p = 0; p < 4; ++p) {
      float v[2];
#pragma unroll
      for (int s = 0; s < 2; ++s) {
        int i = 2 * p + s;
        float val = 0.f;
        if (f < 4) {
          int k = q * 8 + i, ch = f * 16 + c;
          if (k < 12) val = w1l[k * HID + ch];
          else if (k >= 16 && k < 28) val = w1r[(k - 16) * HID + ch];
        } else {
          int t2 = (f - 4) >> 1, half = (f - 4) & 1;
          int k = half * 32 + q * 8 + i;
          int oc = t2 * 16 + c;
          val = (t2 < 2) ? w2l[k * HID2 + oc] : w2r[k * HID2 + (oc - 32)];
        }
        v[s] = val;
      }
      out[p] = packbf(v[0], v[1]);
    }
    *(uint4*)&wfrag[(f * 64 + t) * 4] = make_uint4(out[0], out[1], out[2], out[3]);
  }
}

__global__ __launch_bounds__(256) void scan_buckets(
    const int* __restrict__ bcnt, int* __restrict__ bstart,
    int* __restrict__ bcur, int nb) {
  __shared__ int s[256];
  int t = threadIdx.x;
  int v = (t < nb) ? bcnt[t] : 0;
  s[t] = v;
  __syncthreads();
  for (int d = 1; d < 256; d <<= 1) {
    int a = (t >= d) ? s[t - d] : 0;
    __syncthreads();
    s[t] += a;
    __syncthreads();
  }
  int excl = s[t] - v;
  if (t < nb) { bstart[t] = excl; bcur[t] = excl; }
  if (t == 255) bstart[nb] = s[255];
}

// Reserve per-(block,bucket) chunks, write packed edges bucket-major.
// pack = (dst&1023)<<18 | src  (N < 2^18).
__global__ __launch_bounds__(256) void p2_bin(
    const int* __restrict__ ei, int* __restrict__ bcur,
    unsigned int* __restrict__ binned, int E, int nb) {
  __shared__ int lh[256];
  __shared__ int lbase[256];
  int t = threadIdx.x;
  lh[t] = 0;
  __syncthreads();
  int f64 = detect_f64(ei);
  size_t base = (size_t)blockIdx.x * 8192;
  for (int i = 0; i < 32; ++i) {
    size_t e = base + (size_t)i * 256 + t;
    if (e < (size_t)E) {
      int dst = f64 ? ei[2 * ((size_t)E + e)] : ei[(size_t)E + e];
      atomicAdd(&lh[dst >> 10], 1);
    }
  }
  __syncthreads();
  if (t < nb) {
    int c = lh[t];
    lbase[t] = c ? atomicAdd(&bcur[t], c) : 0;
  }
  __syncthreads();
  lh[t] = 0;
  __syncthreads();
  for (int i = 0; i < 32; ++i) {
    size_t e = base + (size_t)i * 256 + t;
    if (e < (size_t)E) {
      int src, dst;
      if (f64) { src = ei[2 * e]; dst = ei[2 * ((size_t)E + e)]; }
      else     { src = ei[e];     dst = ei[(size_t)E + e]; }
      int b = dst >> 10;
      int lp = atomicAdd(&lh[b], 1);
      binned[lbase[b] + lp] = ((unsigned int)(dst & 1023) << 18) | (unsigned int)src;
    }
  }
}

// One block per bucket (<=1024 nodes). LDS count -> scan -> position atomics.
__global__ __launch_bounds__(1024) void p3_build(
    const unsigned int* __restrict__ binned, const int* __restrict__ bstart,
    int* __restrict__ deg, int* __restrict__ off, int* __restrict__ csr, int N) {
  __shared__ int cnt[1024];
  __shared__ int s[1024];
  __shared__ int cur[1024];
  int t = threadIdx.x;
  int b = blockIdx.x;
  int nbase = b << 10;
  int estart = bstart[b], eend = bstart[b + 1];
  cnt[t] = 0;
  __syncthreads();
  for (int e = estart + t; e < eend; e += 1024) {
    unsigned int p = binned[e];
    atomicAdd(&cnt[p >> 18], 1);
  }
  __syncthreads();
  int v = cnt[t];
  s[t] = v;
  __syncthreads();
  for (int d = 1; d < 1024; d <<= 1) {
    int a = (t >= d) ? s[t - d] : 0;
    __syncthreads();
    s[t] += a;
    __syncthreads();
  }
  int excl = s[t] - v;
  int node = nbase + t;
  if (node < N) { deg[node] = v; off[node] = estart + excl; }
  cur[t] = estart + excl;
  __syncthreads();
  for (int e = estart + t; e < eend; e += 1024) {
    unsigned int p = binned[e];
    int pos = atomicAdd(&cur[p >> 18], 1);
    csr[pos] = (int)(p & 0x3FFFFu);
  }
}

// 4 lanes/node, uint2 gathers, 8-deep ILP. 16 nodes/wave -> 128 lines in flight.
__global__ __launch_bounds__(256) void agg1_mean(
    const int* __restrict__ off, const int* __restrict__ deg,
    const int* __restrict__ csr, unsigned int* __restrict__ inb32, int N) {
  int tid = blockIdx.x * 256 + threadIdx.x;
  int node = tid >> 2;
  int l = tid & 3;
  if (node >= N) return;
  unsigned int* row = inb32 + (size_t)node * 16;
  if (l == 3) { row[6] = 0; row[7] = 0; return; }  // pad ch 12..15
  int start = off[node], d = deg[node];
  float a0 = 0.f, a1 = 0.f, a2 = 0.f, a3 = 0.f;
  if (d > 0) {
    const uint2* xg = (const uint2*)(inb32 + 8) + l;  // +2l u32
    for (int j = 0; j < d; j += 8) {
      uint2 w[8];
#pragma unroll
      for (int k = 0; k < 8; ++k) {
        int jj = j + k;
        int s = csr[start + (jj < d ? jj : 0)];
        uint2 wv = xg[(size_t)s * 8];
        w[k].x = (jj < d) ? wv.x : 0u;
        w[k].y = (jj < d) ? wv.y : 0u;
      }
#pragma unroll
      for (int k = 0; k < 8; ++k) {
        a0 += __uint_as_float(w[k].x << 16);
        a1 += __uint_as_float(w[k].x & 0xffff0000u);
        a2 += __uint_as_float(w[k].y << 16);
        a3 += __uint_as_float(w[k].y & 0xffff0000u);
      }
    }
  }
  float inv = 1.0f / fmaxf((float)d, 1.0f);
  *(uint2*)(row + 2 * l) =
      make_uint2(packbf(a0 * inv, a1 * inv), packbf(a2 * inv, a3 * inv));
}

// MFMA layer1 (R6): per wave one 16-node tile per pass.
__global__ __launch_bounds__(256) void layer1_mfma(
    const unsigned short* __restrict__ in_bf, const unsigned int* __restrict__ wfrag,
    const float* __restrict__ b1, const float* __restrict__ b2,
    unsigned short* __restrict__ g, unsigned short* __restrict__ r, int N) {
  __shared__ unsigned int s_h[4][512];
  int t = threadIdx.x, wave = t >> 6, l = t & 63;
  int q = l >> 4, c = l & 15;
  int swz = c & 7;

  union FU { uint4 u4; bf16x8 v; } fu;
  bf16x8 a1[4], a2[8];
#pragma unroll
  for (int f = 0; f < 4; ++f) { fu.u4 = ((const uint4*)wfrag)[f * 64 + l]; a1[f] = fu.v; }
#pragma unroll
  for (int f = 0; f < 8; ++f) { fu.u4 = ((const uint4*)wfrag)[(4 + f) * 64 + l]; a2[f] = fu.v; }

  f32x4 c1[4], c2[4];
#pragma unroll
  for (int t1 = 0; t1 < 4; ++t1) {
    float4 bv = *(const float4*)(b1 + t1 * 16 + q * 4);
    c1[t1][0] = bv.x; c1[t1][1] = bv.y; c1[t1][2] = bv.z; c1[t1][3] = bv.w;
  }
#pragma unroll
  for (int t2 = 0; t2 < 4; ++t2) {
    if (t2 < 2) { c2[t2][0] = 0.f; c2[t2][1] = 0.f; c2[t2][2] = 0.f; c2[t2][3] = 0.f; }
    else {
      float4 bv = *(const float4*)(b2 + (t2 - 2) * 16 + q * 4);
      c2[t2][0] = bv.x; c2[t2][1] = bv.y; c2[t2][2] = bv.z; c2[t2][3] = bv.w;
    }
  }

  int ntiles = (N + 15) >> 4;
  for (int tile = blockIdx.x * 4 + wave; tile < ntiles; tile += gridDim.x * 4) {
    int node_g = tile * 16 + c;
    int ng = node_g < N ? node_g : N - 1;
    fu.u4 = ((const uint4*)in_bf)[(size_t)ng * 4 + q];
    bf16x8 bfrag = fu.v;

#pragma unroll
    for (int t1 = 0; t1 < 4; ++t1) {
      f32x4 d = __builtin_amdgcn_mfma_f32_16x16x32_bf16(a1[t1], bfrag, c1[t1], 0, 0, 0);
      unsigned int lo = packbf(fmaxf(d[0], 0.f), fmaxf(d[1], 0.f));
      unsigned int hi = packbf(fmaxf(d[2], 0.f), fmaxf(d[3], 0.f));
      int gr = (t1 * 2 + (q >> 1)) ^ swz;
      int idx = c * 32 + gr * 4 + (q & 1) * 2;
      *(uint2*)&s_h[wave][idx] = make_uint2(lo, hi);
    }
    __builtin_amdgcn_wave_barrier();

    bf16x8 hf0, hf1;
    fu.u4 = *(const uint4*)&s_h[wave][c * 32 + ((q) ^ swz) * 4];       hf0 = fu.v;
    fu.u4 = *(const uint4*)&s_h[wave][c * 32 + ((4 + q) ^ swz) * 4];   hf1 = fu.v;

    if (node_g < N) {
      size_t gb = (size_t)node_g * HID2;
#pragma unroll
      for (int t2 = 0; t2 < 4; ++t2) {
        f32x4 d = __builtin_amdgcn_mfma_f32_16x16x32_bf16(a2[t2 * 2 + 0], hf0, c2[t2], 0, 0, 0);
        d = __builtin_amdgcn_mfma_f32_16x16x32_bf16(a2[t2 * 2 + 1], hf1, d, 0, 0, 0);
        unsigned int lo = packbf(d[0], d[1]);
        unsigned int hi = packbf(d[2], d[3]);
        unsigned short* dst = (t2 < 2) ? g : r;
        int ch = (t2 & 1) * 16 + q * 4;
        *(uint2*)(dst + gb + ch) = make_uint2(lo, hi);
      }
    }
    __builtin_amdgcn_wave_barrier();
  }
}

// 8 lanes/node, uint2 gathers, 8-deep ILP. 8 nodes/wave -> 64 lines in flight.
// Lane l owns channels 4l..4l+3.
__global__ __launch_bounds__(256) void agg2_final(
    const int* __restrict__ off, const int* __restrict__ deg,
    const int* __restrict__ csr, const unsigned int* __restrict__ g32,
    const unsigned int* __restrict__ r32, const float* __restrict__ wc,
    const float* __restrict__ bc, float* __restrict__ out, int N) {
  int tid = blockIdx.x * 256 + threadIdx.x;
  int node = tid >> 3;
  int lane = tid & 7;
  if (node >= N) return;
  int start = off[node], d = deg[node];
  float a0 = 0.f, a1 = 0.f, a2 = 0.f, a3 = 0.f;
  if (d > 0) {
    const uint2* gl = (const uint2*)g32 + lane;  // +2*lane u32 within row
    for (int j = 0; j < d; j += 8) {
      uint2 w[8];
#pragma unroll
      for (int k = 0; k < 8; ++k) {
        int jj = j + k;
        int s = csr[start + (jj < d ? jj : 0)];
        uint2 wv = gl[(size_t)s * 8];
        w[k].x = (jj < d) ? wv.x : 0u;
        w[k].y = (jj < d) ? wv.y : 0u;
      }
#pragma unroll
      for (int k = 0; k < 8; ++k) {
        a0 += __uint_as_float(w[k].x << 16);
        a1 += __uint_as_float(w[k].x & 0xffff0000u);
        a2 += __uint_as_float(w[k].y << 16);
        a3 += __uint_as_float(w[k].y & 0xffff0000u);
      }
    }
  }
  float dg = fmaxf((float)d, 1.0f);
  float inv = 1.0f / dg;
  uint2 rw = *((const uint2*)r32 + (size_t)node * 8 + lane);
  float v0 = fmaxf(a0 * inv + __uint_as_float(rw.x << 16), 0.0f);
  float v1 = fmaxf(a1 * inv + __uint_as_float(rw.x & 0xffff0000u), 0.0f);
  float v2 = fmaxf(a2 * inv + __uint_as_float(rw.y << 16), 0.0f);
  float v3 = fmaxf(a3 * inv + __uint_as_float(rw.y & 0xffff0000u), 0.0f);
  int ch = lane * 4;
  float p0 = v0 * wc[(ch + 0) * 2] + v1 * wc[(ch + 1) * 2] +
             v2 * wc[(ch + 2) * 2] + v3 * wc[(ch + 3) * 2];
  float p1 = v0 * wc[(ch + 0) * 2 + 1] + v1 * wc[(ch + 1) * 2 + 1] +
             v2 * wc[(ch + 2) * 2 + 1] + v3 * wc[(ch + 3) * 2 + 1];
#pragma unroll
  for (int o2 = 4; o2 > 0; o2 >>= 1) {
    p0 += __shfl_down(p0, o2, 8);
    p1 += __shfl_down(p1, o2, 8);
  }
  if (lane == 0) {
    out[(size_t)node * 2 + 0] = p0 + bc[0];
    out[(size_t)node * 2 + 1] = p1 + bc[1];
  }
}

extern "C" void kernel_launch(void* const* d_in, const int* in_sizes, int n_in,
                              void* d_out, int out_size, void* d_ws, size_t ws_size,
                              hipStream_t stream) {
  const float* x   = (const float*)d_in[0];
  const int*   ei  = (const int*)d_in[1];
  const float* w1l = (const float*)d_in[2];
  const float* b1  = (const float*)d_in[3];
  const float* w1r = (const float*)d_in[4];
  const float* w2l = (const float*)d_in[5];
  const float* b2  = (const float*)d_in[6];
  const float* w2r = (const float*)d_in[7];
  const float* wc  = (const float*)d_in[8];
  const float* bc  = (const float*)d_in[9];
  float* out = (float*)d_out;

  int N = in_sizes[0] / IN_CH;
  int E = in_sizes[1] / 2;
  int nb = (N + 1023) >> 10;  // 196 buckets

  // ws ints: deg[N] off[N] bmeta[772] csr[E] binned[E]
  //   bmeta: bcnt=+0(256), bstart=+256(257), bcur=+513(256)
  // then u32 inb32[N*16] | u16 g[N*32] r[N*32] | u32 wfrag[3072]
  int* deg    = (int*)d_ws;
  int* off    = deg + N;
  int* bmeta  = off + N;
  int* bcnt   = bmeta;
  int* bstart = bmeta + 256;
  int* bcur   = bmeta + 513;
  int* csr    = bmeta + 772;
  unsigned int* binned = (unsigned int*)(csr + E);
  unsigned int* inb32  = binned + E;
  unsigned short* inb  = (unsigned short*)inb32;
  unsigned int* g32    = inb32 + (size_t)N * 16;
  unsigned short* g    = (unsigned short*)g32;
  unsigned int* r32    = g32 + (size_t)N * 16;
  unsigned short* r    = (unsigned short*)r32;
  unsigned int* wfrag  = r32 + (size_t)N * 16;

  hipMemsetAsync(bcnt, 0, 256 * sizeof(int), stream);

  int histB  = (E + 8191) / 8192;
  int xcastB = (N * 8 + 255) / 256;
  fused_pre<<<histB + xcastB + 12, 256, 0, stream>>>(
      ei, bcnt, x, inb32, w1l, w1r, w2l, w2r, wfrag, E, N, nb, histB, xcastB);

  scan_buckets<<<1, 256, 0, stream>>>(bcnt, bstart, bcur, nb);
  p2_bin<<<histB, 256, 0, stream>>>(ei, bcur, binned, E, nb);
  p3_build<<<nb, 1024, 0, stream>>>(binned, bstart, deg, off, csr, N);

  agg1_mean<<<((size_t)N * 4 + 255) / 256, 256, 0, stream>>>(off, deg, csr, inb32, N);

  layer1_mfma<<<1024, 256, 0, stream>>>(inb, wfrag, b1, b2, g, r, N);

  agg2_final<<<((size_t)N * 8 + 255) / 256, 256, 0, stream>>>(
      off, deg, csr, g32, r32, wc, bc, out, N);
}